// Round 1
// baseline (2996.061 us; speedup 1.0000x reference)
//
#include <hip/hip_runtime.h>
#include <hip/hip_bf16.h>

#define HID 64
#define NEG_SLOP 0.2f

__device__ __forceinline__ float lrelu(float v) {
    return v > 0.0f ? v : NEG_SLOP * v;
}

// ---------------- degree / dinv ----------------
__global__ void deg_kernel(const int* __restrict__ dst, const float* __restrict__ ew,
                           float* __restrict__ deg, int n_edges) {
    int e = blockIdx.x * 256 + threadIdx.x;
    if (e >= n_edges) return;
    atomicAdd(&deg[dst[e]], ew[e]);
}

__global__ void dinv_kernel(const float* __restrict__ deg, float* __restrict__ dinv, int n) {
    int i = blockIdx.x * 256 + threadIdx.x;
    if (i >= n) return;
    float d = deg[i] + 1.0f;  // self loop
    dinv[i] = rsqrtf(d);
}

// ---------------- skinny GEMM: [n_rows x K] @ [K x 64] ----------------
// in has row stride in_stride (cat rows are stride 256). 16 rows/block, 256 thr.
__global__ void gemm_skinny(const float* __restrict__ in, int in_stride, int K,
                            const float* __restrict__ W, float* __restrict__ out,
                            int n_rows) {
    __shared__ float Ws[128 * 64];
    int tid = threadIdx.x;
    for (int i = tid; i < K * 64; i += 256) Ws[i] = W[i];
    __syncthreads();
    int row = blockIdx.x * 16 + (tid >> 4);
    if (row >= n_rows) return;
    int c0 = (tid & 15) * 4;
    float a0 = 0.f, a1 = 0.f, a2 = 0.f, a3 = 0.f;
    const float* xr = in + (size_t)row * in_stride;
    for (int k = 0; k < K; ++k) {
        float a = xr[k];
        const float* w = &Ws[k * 64 + c0];
        a0 += a * w[0]; a1 += a * w[1]; a2 += a * w[2]; a3 += a * w[3];
    }
    float4 r = make_float4(a0, a1, a2, a3);
    *(float4*)&out[(size_t)row * 64 + c0] = r;
}

// ---------------- edge scatter (layer 1: no norm) ----------------
// 16 lanes per edge, each lane handles 4 consecutive features (float4).
__global__ void scatter_plain(const int* __restrict__ src, const int* __restrict__ dst,
                              const float* __restrict__ ew, const float* __restrict__ hW,
                              float* __restrict__ agg, int n_edges) {
    int t = blockIdx.x * 256 + threadIdx.x;
    int e = t >> 4;
    if (e >= n_edges) return;
    int lane = (t & 15) * 4;
    int s = src[e], d = dst[e];
    float w = ew[e];
    float4 v = *(const float4*)&hW[(size_t)s * HID + lane];
    float* a = &agg[(size_t)d * HID + lane];
    atomicAdd(a + 0, v.x * w);
    atomicAdd(a + 1, v.y * w);
    atomicAdd(a + 2, v.z * w);
    atomicAdd(a + 3, v.w * w);
}

// ---------------- edge scatter (normalized layers) ----------------
__global__ void scatter_norm(const int* __restrict__ src, const int* __restrict__ dst,
                             const float* __restrict__ ew, const float* __restrict__ dinv,
                             const float* __restrict__ hW, float* __restrict__ agg,
                             int n_edges) {
    int t = blockIdx.x * 256 + threadIdx.x;
    int e = t >> 4;
    if (e >= n_edges) return;
    int lane = (t & 15) * 4;
    int s = src[e], d = dst[e];
    float w = ew[e] * dinv[s] * dinv[d];
    float4 v = *(const float4*)&hW[(size_t)s * HID + lane];
    float* a = &agg[(size_t)d * HID + lane];
    atomicAdd(a + 0, v.x * w);
    atomicAdd(a + 1, v.y * w);
    atomicAdd(a + 2, v.z * w);
    atomicAdd(a + 3, v.w * w);
}

// ---------------- finalize layer 1: cat[:,0:64] = lrelu(agg + b) ----------------
__global__ void finalize_plain(const float* __restrict__ agg, const float* __restrict__ b,
                               float* __restrict__ cat, int n_nodes) {
    int t = blockIdx.x * 256 + threadIdx.x;      // one float4 per thread
    if (t >= n_nodes * 16) return;
    int node = t >> 4;
    int f0 = (t & 15) * 4;
    float4 v = *(const float4*)&agg[(size_t)node * HID + f0];
    v.x = lrelu(v.x + b[f0 + 0]);
    v.y = lrelu(v.y + b[f0 + 1]);
    v.z = lrelu(v.z + b[f0 + 2]);
    v.w = lrelu(v.w + b[f0 + 3]);
    *(float4*)&cat[(size_t)node * 256 + f0] = v;
}

// ---------------- finalize norm layers: cat[:,l*64:..] = lrelu(agg + dinv^2*hW + b) ----------------
__global__ void finalize_norm(const float* __restrict__ agg, const float* __restrict__ hW,
                              const float* __restrict__ dinv, const float* __restrict__ b,
                              float* __restrict__ cat, int col_off, int n_nodes) {
    int t = blockIdx.x * 256 + threadIdx.x;
    if (t >= n_nodes * 16) return;
    int node = t >> 4;
    int f0 = (t & 15) * 4;
    float di = dinv[node];
    float self = di * di;
    float4 v = *(const float4*)&agg[(size_t)node * HID + f0];
    float4 h = *(const float4*)&hW[(size_t)node * HID + f0];
    v.x = lrelu(v.x + self * h.x + b[f0 + 0]);
    v.y = lrelu(v.y + self * h.y + b[f0 + 1]);
    v.z = lrelu(v.z + self * h.z + b[f0 + 2]);
    v.w = lrelu(v.w + self * h.w + b[f0 + 3]);
    *(float4*)&cat[(size_t)node * 256 + col_off + f0] = v;
}

// ---------------- final GEMM: [N x 256] @ [256 x 128] + bh ----------------
// 16 rows/block, 256 threads; K chunked by 64 through 32KB LDS.
__global__ void gemm_final(const float* __restrict__ cat, const float* __restrict__ Wh,
                           const float* __restrict__ bh, float* __restrict__ out,
                           int n_rows) {
    __shared__ float Ws[64 * 128];
    int tid = threadIdx.x;
    int row = blockIdx.x * 16 + (tid >> 4);
    int c0 = (tid & 15) * 8;
    float acc[8] = {0.f, 0.f, 0.f, 0.f, 0.f, 0.f, 0.f, 0.f};
    for (int kc = 0; kc < 4; ++kc) {
        __syncthreads();
        for (int i = tid; i < 64 * 128; i += 256) Ws[i] = Wh[kc * 64 * 128 + i];
        __syncthreads();
        if (row < n_rows) {
            const float* xr = cat + (size_t)row * 256 + kc * 64;
            for (int k = 0; k < 64; ++k) {
                float a = xr[k];
                const float* w = &Ws[k * 128 + c0];
#pragma unroll
                for (int j = 0; j < 8; ++j) acc[j] += a * w[j];
            }
        }
    }
    if (row >= n_rows) return;
#pragma unroll
    for (int j = 0; j < 8; ++j) acc[j] += bh[c0 + j];
    *(float4*)&out[(size_t)row * 128 + c0] = make_float4(acc[0], acc[1], acc[2], acc[3]);
    *(float4*)&out[(size_t)row * 128 + c0 + 4] = make_float4(acc[4], acc[5], acc[6], acc[7]);
}

extern "C" void kernel_launch(void* const* d_in, const int* in_sizes, int n_in,
                              void* d_out, int out_size, void* d_ws, size_t ws_size,
                              hipStream_t stream) {
    const float* x  = (const float*)d_in[0];
    const int*   ei = (const int*)d_in[1];
    const float* ew = (const float*)d_in[2];
    const float* W1 = (const float*)d_in[3];
    const float* b1 = (const float*)d_in[4];
    const float* W2 = (const float*)d_in[5];
    const float* b2 = (const float*)d_in[6];
    const float* W3 = (const float*)d_in[7];
    const float* b3 = (const float*)d_in[8];
    const float* W4 = (const float*)d_in[9];
    const float* b4 = (const float*)d_in[10];
    const float* Wh = (const float*)d_in[11];
    const float* bh = (const float*)d_in[12];

    const int E = in_sizes[2];          // 800000 (edge_weight count)
    const int N = in_sizes[0] / 128;    // 50000
    const int* src = ei;
    const int* dst = ei + E;

    float* ws   = (float*)d_ws;
    float* cat  = ws;                         // N*256
    float* hW   = cat + (size_t)N * 256;      // N*64
    float* agg  = hW  + (size_t)N * 64;       // N*64
    float* deg  = agg + (size_t)N * 64;       // N
    float* dinv = deg + N;                    // N
    float* out  = (float*)d_out;

    int eb  = (E + 255) / 256;                // 1 thread / edge
    int eb16 = (E * 16 + 255) / 256;          // 16 threads / edge
    int nb  = (N + 255) / 256;
    int nb16 = (N * 16 + 255) / 256;
    int gb  = (N + 15) / 16;                  // gemm blocks (16 rows each)

    // degree + dinv (used by layers 2-4)
    hipMemsetAsync(deg, 0, (size_t)N * sizeof(float), stream);
    deg_kernel<<<eb, 256, 0, stream>>>(dst, ew, deg, E);
    dinv_kernel<<<nb, 256, 0, stream>>>(deg, dinv, N);

    // ---- layer 1 (no norm) ----
    gemm_skinny<<<gb, 256, 0, stream>>>(x, 128, 128, W1, hW, N);
    hipMemsetAsync(agg, 0, (size_t)N * 64 * sizeof(float), stream);
    scatter_plain<<<eb16, 256, 0, stream>>>(src, dst, ew, hW, agg, E);
    finalize_plain<<<nb16, 256, 0, stream>>>(agg, b1, cat, N);

    // ---- layers 2-4 (normalized) ----
    const float* Wl[3] = {W2, W3, W4};
    const float* bl[3] = {b2, b3, b4};
    for (int l = 1; l < 4; ++l) {
        gemm_skinny<<<gb, 256, 0, stream>>>(cat + (size_t)(l - 1) * 64, 256, 64,
                                            Wl[l - 1], hW, N);
        hipMemsetAsync(agg, 0, (size_t)N * 64 * sizeof(float), stream);
        scatter_norm<<<eb16, 256, 0, stream>>>(src, dst, ew, dinv, hW, agg, E);
        finalize_norm<<<nb16, 256, 0, stream>>>(agg, hW, dinv, bl[l - 1], cat, l * 64, N);
    }

    // ---- final projection ----
    gemm_final<<<gb, 256, 0, stream>>>(cat, Wh, bh, out, N);
}

// Round 2
// 573.871 us; speedup vs baseline: 5.2208x; 5.2208x over previous
//
#include <hip/hip_runtime.h>
#include <hip/hip_bf16.h>

#define HID 64
#define NEG_SLOP 0.2f

__device__ __forceinline__ float lrelu(float v) {
    return v > 0.0f ? v : NEG_SLOP * v;
}

// ---------------- histogram: weighted degree + in-degree count ----------------
__global__ void histo_kernel(const int* __restrict__ dst, const float* __restrict__ ew,
                             float* __restrict__ deg, int* __restrict__ cnt, int n_edges) {
    int e = blockIdx.x * 256 + threadIdx.x;
    if (e >= n_edges) return;
    int d = dst[e];
    atomicAdd(&deg[d], ew[e]);
    atomicAdd(&cnt[d], 1);
}

__global__ void dinv_kernel(const float* __restrict__ deg, float* __restrict__ dinv, int n) {
    int i = blockIdx.x * 256 + threadIdx.x;
    if (i >= n) return;
    float d = deg[i] + 1.0f;  // self loop
    dinv[i] = rsqrtf(d);
}

// ---------------- single-block exclusive scan of cnt -> row_ptr, cursor ----------------
__global__ void scan_kernel(const int* __restrict__ cnt, int* __restrict__ row_ptr,
                            int* __restrict__ cursor, int n) {
    __shared__ int s[1024];
    int t = threadIdx.x;
    const int chunk = (n + 1023) / 1024;
    int lo = t * chunk;
    int hi = lo + chunk; if (hi > n) hi = n;
    int local = 0;
    for (int i = lo; i < hi; ++i) local += cnt[i];
    s[t] = local;
    __syncthreads();
    for (int off = 1; off < 1024; off <<= 1) {
        int v = (t >= off) ? s[t - off] : 0;
        __syncthreads();
        s[t] += v;
        __syncthreads();
    }
    int run = s[t] - local;  // exclusive prefix of this chunk
    for (int i = lo; i < hi; ++i) {
        row_ptr[i] = run;
        cursor[i] = run;
        run += cnt[i];
    }
    if (t == 1023) row_ptr[n] = s[1023];
}

// ---------------- CSR fill: place edges bucketed by dst ----------------
__global__ void fill_kernel(const int* __restrict__ src, const int* __restrict__ dst,
                            const float* __restrict__ ew, const float* __restrict__ dinv,
                            int* __restrict__ cursor, int* __restrict__ e_src,
                            float* __restrict__ e_w, float* __restrict__ e_wn, int n_edges) {
    int e = blockIdx.x * 256 + threadIdx.x;
    if (e >= n_edges) return;
    int s = src[e], d = dst[e];
    float w = ew[e];
    int pos = atomicAdd(&cursor[d], 1);
    e_src[pos] = s;
    e_w[pos] = w;
    e_wn[pos] = w * dinv[s] * dinv[d];
}

// ---------------- layer 1 gather (no norm): cat[:,0:64] = lrelu(sum + b) ----------------
// 16 lanes per node, float4 per lane.
__global__ void gather_plain(const int* __restrict__ row_ptr, const int* __restrict__ e_src,
                             const float* __restrict__ e_w, const float* __restrict__ hW,
                             const float* __restrict__ b, float* __restrict__ cat,
                             int n_nodes) {
    int t = blockIdx.x * 256 + threadIdx.x;
    int node = t >> 4;
    if (node >= n_nodes) return;
    int f0 = (t & 15) * 4;
    int lo = row_ptr[node], hi = row_ptr[node + 1];
    float a0 = 0.f, a1 = 0.f, a2 = 0.f, a3 = 0.f;
    for (int k = lo; k < hi; ++k) {
        int s = e_src[k];
        float w = e_w[k];
        float4 v = *(const float4*)&hW[(size_t)s * HID + f0];
        a0 += w * v.x; a1 += w * v.y; a2 += w * v.z; a3 += w * v.w;
    }
    a0 = lrelu(a0 + b[f0 + 0]);
    a1 = lrelu(a1 + b[f0 + 1]);
    a2 = lrelu(a2 + b[f0 + 2]);
    a3 = lrelu(a3 + b[f0 + 3]);
    *(float4*)&cat[(size_t)node * 256 + f0] = make_float4(a0, a1, a2, a3);
}

// ---------------- norm layer gather: cat[:,off..] = lrelu(sum + dinv^2*hW[node] + b) ----------------
__global__ void gather_norm(const int* __restrict__ row_ptr, const int* __restrict__ e_src,
                            const float* __restrict__ e_wn, const float* __restrict__ hW,
                            const float* __restrict__ dinv, const float* __restrict__ b,
                            float* __restrict__ cat, int col_off, int n_nodes) {
    int t = blockIdx.x * 256 + threadIdx.x;
    int node = t >> 4;
    if (node >= n_nodes) return;
    int f0 = (t & 15) * 4;
    int lo = row_ptr[node], hi = row_ptr[node + 1];
    float a0 = 0.f, a1 = 0.f, a2 = 0.f, a3 = 0.f;
    for (int k = lo; k < hi; ++k) {
        int s = e_src[k];
        float w = e_wn[k];
        float4 v = *(const float4*)&hW[(size_t)s * HID + f0];
        a0 += w * v.x; a1 += w * v.y; a2 += w * v.z; a3 += w * v.w;
    }
    float di = dinv[node];
    float self = di * di;
    float4 h = *(const float4*)&hW[(size_t)node * HID + f0];
    a0 = lrelu(a0 + self * h.x + b[f0 + 0]);
    a1 = lrelu(a1 + self * h.y + b[f0 + 1]);
    a2 = lrelu(a2 + self * h.z + b[f0 + 2]);
    a3 = lrelu(a3 + self * h.w + b[f0 + 3]);
    *(float4*)&cat[(size_t)node * 256 + col_off + f0] = make_float4(a0, a1, a2, a3);
}

// ---------------- skinny GEMM: [n_rows x K] @ [K x 64] ----------------
__global__ void gemm_skinny(const float* __restrict__ in, int in_stride, int K,
                            const float* __restrict__ W, float* __restrict__ out,
                            int n_rows) {
    __shared__ float Ws[128 * 64];
    int tid = threadIdx.x;
    for (int i = tid; i < K * 64; i += 256) Ws[i] = W[i];
    __syncthreads();
    int row = blockIdx.x * 16 + (tid >> 4);
    if (row >= n_rows) return;
    int c0 = (tid & 15) * 4;
    float a0 = 0.f, a1 = 0.f, a2 = 0.f, a3 = 0.f;
    const float* xr = in + (size_t)row * in_stride;
    for (int k = 0; k < K; ++k) {
        float a = xr[k];
        const float* w = &Ws[k * 64 + c0];
        a0 += a * w[0]; a1 += a * w[1]; a2 += a * w[2]; a3 += a * w[3];
    }
    *(float4*)&out[(size_t)row * 64 + c0] = make_float4(a0, a1, a2, a3);
}

// ---------------- final GEMM: [N x 256] @ [256 x 128] + bh ----------------
__global__ void gemm_final(const float* __restrict__ cat, const float* __restrict__ Wh,
                           const float* __restrict__ bh, float* __restrict__ out,
                           int n_rows) {
    __shared__ float Ws[64 * 128];
    int tid = threadIdx.x;
    int row = blockIdx.x * 16 + (tid >> 4);
    int c0 = (tid & 15) * 8;
    float acc[8] = {0.f, 0.f, 0.f, 0.f, 0.f, 0.f, 0.f, 0.f};
    for (int kc = 0; kc < 4; ++kc) {
        __syncthreads();
        for (int i = tid; i < 64 * 128; i += 256) Ws[i] = Wh[kc * 64 * 128 + i];
        __syncthreads();
        if (row < n_rows) {
            const float* xr = cat + (size_t)row * 256 + kc * 64;
            for (int k = 0; k < 64; ++k) {
                float a = xr[k];
                const float* w = &Ws[k * 128 + c0];
#pragma unroll
                for (int j = 0; j < 8; ++j) acc[j] += a * w[j];
            }
        }
    }
    if (row >= n_rows) return;
#pragma unroll
    for (int j = 0; j < 8; ++j) acc[j] += bh[c0 + j];
    *(float4*)&out[(size_t)row * 128 + c0] = make_float4(acc[0], acc[1], acc[2], acc[3]);
    *(float4*)&out[(size_t)row * 128 + c0 + 4] = make_float4(acc[4], acc[5], acc[6], acc[7]);
}

extern "C" void kernel_launch(void* const* d_in, const int* in_sizes, int n_in,
                              void* d_out, int out_size, void* d_ws, size_t ws_size,
                              hipStream_t stream) {
    const float* x  = (const float*)d_in[0];
    const int*   ei = (const int*)d_in[1];
    const float* ew = (const float*)d_in[2];
    const float* W1 = (const float*)d_in[3];
    const float* b1 = (const float*)d_in[4];
    const float* W2 = (const float*)d_in[5];
    const float* b2 = (const float*)d_in[6];
    const float* W3 = (const float*)d_in[7];
    const float* b3 = (const float*)d_in[8];
    const float* W4 = (const float*)d_in[9];
    const float* b4 = (const float*)d_in[10];
    const float* Wh = (const float*)d_in[11];
    const float* bh = (const float*)d_in[12];

    const int E = in_sizes[2];          // 800000
    const int N = in_sizes[0] / 128;    // 50000
    const int* src = ei;
    const int* dst = ei + E;

    // workspace layout (floats/ints, 4B each)
    char* p = (char*)d_ws;
    float* cat     = (float*)p;                 p += (size_t)N * 256 * 4;
    float* hW      = (float*)p;                 p += (size_t)N * 64 * 4;
    float* deg     = (float*)p;                 p += (size_t)N * 4;   // deg,cnt adjacent: one memset
    int*   cnt     = (int*)p;                   p += (size_t)N * 4;
    float* dinv    = (float*)p;                 p += (size_t)N * 4;
    int*   row_ptr = (int*)p;                   p += (size_t)(N + 1) * 4;
    int*   cursor  = (int*)p;                   p += (size_t)N * 4;
    int*   e_src   = (int*)p;                   p += (size_t)E * 4;
    float* e_w     = (float*)p;                 p += (size_t)E * 4;
    float* e_wn    = (float*)p;                 p += (size_t)E * 4;
    float* out = (float*)d_out;

    int eb   = (E + 255) / 256;
    int nb   = (N + 255) / 256;
    int nb16 = (N * 16 + 255) / 256;
    int gb   = (N + 15) / 16;

    // ---- CSR build ----
    hipMemsetAsync(deg, 0, (size_t)N * 2 * 4, stream);  // deg + cnt
    histo_kernel<<<eb, 256, 0, stream>>>(dst, ew, deg, cnt, E);
    dinv_kernel<<<nb, 256, 0, stream>>>(deg, dinv, N);
    scan_kernel<<<1, 1024, 0, stream>>>(cnt, row_ptr, cursor, N);
    fill_kernel<<<eb, 256, 0, stream>>>(src, dst, ew, dinv, cursor, e_src, e_w, e_wn, E);

    // ---- layer 1 (no norm) ----
    gemm_skinny<<<gb, 256, 0, stream>>>(x, 128, 128, W1, hW, N);
    gather_plain<<<nb16, 256, 0, stream>>>(row_ptr, e_src, e_w, hW, b1, cat, N);

    // ---- layers 2-4 (normalized) ----
    const float* Wl[3] = {W2, W3, W4};
    const float* bl[3] = {b2, b3, b4};
    for (int l = 1; l < 4; ++l) {
        gemm_skinny<<<gb, 256, 0, stream>>>(cat + (size_t)(l - 1) * 64, 256, 64,
                                            Wl[l - 1], hW, N);
        gather_norm<<<nb16, 256, 0, stream>>>(row_ptr, e_src, e_wn, hW, dinv,
                                              bl[l - 1], cat, l * 64, N);
    }

    // ---- final projection ----
    gemm_final<<<gb, 256, 0, stream>>>(cat, Wh, bh, out, N);
}

// Round 3
// 494.162 us; speedup vs baseline: 6.0629x; 1.1613x over previous
//
#include <hip/hip_runtime.h>
#include <hip/hip_bf16.h>

#define NEG_SLOP 0.2f

__device__ __forceinline__ float lrelu(float v) { return v > 0.0f ? v : NEG_SLOP * v; }

__device__ __forceinline__ float bf2f(unsigned short u) {
    union { unsigned int i; float f; } c; c.i = ((unsigned int)u) << 16; return c.f;
}
__device__ __forceinline__ unsigned short f2bf(float f) {
    union { float f; unsigned int i; } c; c.f = f;
    unsigned int r = c.i + 0x7FFF + ((c.i >> 16) & 1);  // round-nearest-even
    return (unsigned short)(r >> 16);
}

// ---------------- CSR build ----------------
__global__ void histo_kernel(const int* __restrict__ dst, const float* __restrict__ ew,
                             float* __restrict__ deg, int* __restrict__ cnt, int n_edges) {
    int e = blockIdx.x * 256 + threadIdx.x;
    if (e >= n_edges) return;
    int d = dst[e];
    atomicAdd(&deg[d], ew[e]);
    atomicAdd(&cnt[d], 1);
}

__global__ void dinv_kernel(const float* __restrict__ deg, float* __restrict__ dinv, int n) {
    int i = blockIdx.x * 256 + threadIdx.x;
    if (i >= n) return;
    dinv[i] = rsqrtf(deg[i] + 1.0f);
}

__global__ void scan_kernel(const int* __restrict__ cnt, int* __restrict__ row_ptr,
                            int* __restrict__ cursor, int n) {
    __shared__ int s[1024];
    int t = threadIdx.x;
    const int chunk = (n + 1023) / 1024;
    int lo = t * chunk;
    int hi = lo + chunk; if (hi > n) hi = n;
    int local = 0;
    for (int i = lo; i < hi; ++i) local += cnt[i];
    s[t] = local;
    __syncthreads();
    for (int off = 1; off < 1024; off <<= 1) {
        int v = (t >= off) ? s[t - off] : 0;
        __syncthreads();
        s[t] += v;
        __syncthreads();
    }
    int run = s[t] - local;
    for (int i = lo; i < hi; ++i) {
        row_ptr[i] = run;
        cursor[i] = run;
        run += cnt[i];
    }
    if (t == 1023) row_ptr[n] = s[1023];
}

__global__ void fill_kernel(const int* __restrict__ src, const int* __restrict__ dst,
                            const float* __restrict__ ew, const float* __restrict__ dinv,
                            int* __restrict__ cursor, int* __restrict__ e_src,
                            float* __restrict__ e_w, float* __restrict__ e_wn, int n_edges) {
    int e = blockIdx.x * 256 + threadIdx.x;
    if (e >= n_edges) return;
    int s = src[e], d = dst[e];
    float w = ew[e];
    int pos = atomicAdd(&cursor[d], 1);
    e_src[pos] = s;
    e_w[pos] = w;
    e_wn[pos] = w * dinv[s] * dinv[d];
}

// ---------------- gathers (hW in bf16) ----------------
__global__ void gather_plain(const int* __restrict__ rp, const int* __restrict__ es,
                             const float* __restrict__ ewt, const unsigned short* __restrict__ hb,
                             const float* __restrict__ b, float* __restrict__ cat, int n) {
    int t = blockIdx.x * 256 + threadIdx.x;
    int node = t >> 4;
    if (node >= n) return;
    int f0 = (t & 15) * 4;
    int lo = rp[node], hi = rp[node + 1];
    float a0 = 0.f, a1 = 0.f, a2 = 0.f, a3 = 0.f;
    for (int k = lo; k < hi; ++k) {
        int s = es[k];
        float w = ewt[k];
        ushort4 u = *(const ushort4*)&hb[(size_t)s * 64 + f0];
        a0 += w * bf2f(u.x); a1 += w * bf2f(u.y);
        a2 += w * bf2f(u.z); a3 += w * bf2f(u.w);
    }
    a0 = lrelu(a0 + b[f0 + 0]); a1 = lrelu(a1 + b[f0 + 1]);
    a2 = lrelu(a2 + b[f0 + 2]); a3 = lrelu(a3 + b[f0 + 3]);
    *(float4*)&cat[(size_t)node * 256 + f0] = make_float4(a0, a1, a2, a3);
}

__global__ void gather_norm(const int* __restrict__ rp, const int* __restrict__ es,
                            const float* __restrict__ ewn, const unsigned short* __restrict__ hb,
                            const float* __restrict__ dinv, const float* __restrict__ b,
                            float* __restrict__ cat, int col_off, int n) {
    int t = blockIdx.x * 256 + threadIdx.x;
    int node = t >> 4;
    if (node >= n) return;
    int f0 = (t & 15) * 4;
    int lo = rp[node], hi = rp[node + 1];
    float a0 = 0.f, a1 = 0.f, a2 = 0.f, a3 = 0.f;
    for (int k = lo; k < hi; ++k) {
        int s = es[k];
        float w = ewn[k];
        ushort4 u = *(const ushort4*)&hb[(size_t)s * 64 + f0];
        a0 += w * bf2f(u.x); a1 += w * bf2f(u.y);
        a2 += w * bf2f(u.z); a3 += w * bf2f(u.w);
    }
    float di = dinv[node];
    float self = di * di;
    ushort4 h = *(const ushort4*)&hb[(size_t)node * 64 + f0];
    a0 = lrelu(a0 + self * bf2f(h.x) + b[f0 + 0]);
    a1 = lrelu(a1 + self * bf2f(h.y) + b[f0 + 1]);
    a2 = lrelu(a2 + self * bf2f(h.z) + b[f0 + 2]);
    a3 = lrelu(a3 + self * bf2f(h.w) + b[f0 + 3]);
    *(float4*)&cat[(size_t)node * 256 + col_off + f0] = make_float4(a0, a1, a2, a3);
}

// ---------------- skinny GEMM: [N x K] @ [K x 64] -> bf16 hW ----------------
// 128-row tile, 256 threads = 16 col-groups x 16 row-groups; thread = 8 rows x 4 cols.
__global__ __launch_bounds__(256) void gemm_hid(
    const float* __restrict__ in, int in_stride, int K,
    const float* __restrict__ W, unsigned short* __restrict__ outb, int n_rows) {
    __shared__ float Ws[64 * 64];
    __shared__ float XsT[64 * 132];   // [k][row], padded row-dim 132
    const int tid = threadIdx.x;
    const int tc = tid & 15, tr = tid >> 4;
    const int row0 = blockIdx.x * 128;
    float acc[8][4] = {};
    for (int kc = 0; kc < K; kc += 64) {
        __syncthreads();
        for (int i = tid; i < 64 * 64; i += 256) Ws[i] = W[kc * 64 + i];
        {   // stage A transposed: thread handles k = tid&63, rows (tid>>6)*32 .. +31
            int k = tid & 63, rq = tid >> 6;
            for (int i = 0; i < 32; ++i) {
                int r = rq * 32 + i;
                int rr = row0 + r; if (rr >= n_rows) rr = n_rows - 1;
                XsT[k * 132 + r] = in[(size_t)rr * in_stride + kc + k];
            }
        }
        __syncthreads();
        for (int kk = 0; kk < 64; ++kk) {
            float4 w4 = *(const float4*)&Ws[kk * 64 + tc * 4];
            float4 aA = *(const float4*)&XsT[kk * 132 + tr * 8];
            float4 aB = *(const float4*)&XsT[kk * 132 + tr * 8 + 4];
            float a[8] = {aA.x, aA.y, aA.z, aA.w, aB.x, aB.y, aB.z, aB.w};
#pragma unroll
            for (int i = 0; i < 8; ++i) {
                acc[i][0] += a[i] * w4.x; acc[i][1] += a[i] * w4.y;
                acc[i][2] += a[i] * w4.z; acc[i][3] += a[i] * w4.w;
            }
        }
    }
#pragma unroll
    for (int i = 0; i < 8; ++i) {
        int r = row0 + tr * 8 + i;
        if (r >= n_rows) break;
        ushort4 o;
        o.x = f2bf(acc[i][0]); o.y = f2bf(acc[i][1]);
        o.z = f2bf(acc[i][2]); o.w = f2bf(acc[i][3]);
        *(ushort4*)&outb[(size_t)r * 64 + tc * 4] = o;
    }
}

// ---------------- final GEMM: [N x 256] @ [256 x 128] + bh ----------------
// 128-row tile; thread = 8 rows x 8 cols (cols tc*4 and 64+tc*4).
__global__ __launch_bounds__(256) void gemm_out(
    const float* __restrict__ cat, const float* __restrict__ Wh,
    const float* __restrict__ bh, float* __restrict__ out, int n_rows) {
    __shared__ float Ws[64 * 128];
    __shared__ float XsT[64 * 132];
    const int tid = threadIdx.x;
    const int tc = tid & 15, tr = tid >> 4;
    const int row0 = blockIdx.x * 128;
    float acc[8][8] = {};
    for (int kc = 0; kc < 256; kc += 64) {
        __syncthreads();
        for (int i = tid; i < 64 * 128; i += 256) Ws[i] = Wh[kc * 128 + i];
        {
            int k = tid & 63, rq = tid >> 6;
            for (int i = 0; i < 32; ++i) {
                int r = rq * 32 + i;
                int rr = row0 + r; if (rr >= n_rows) rr = n_rows - 1;
                XsT[k * 132 + r] = cat[(size_t)rr * 256 + kc + k];
            }
        }
        __syncthreads();
        for (int kk = 0; kk < 64; ++kk) {
            float4 wA = *(const float4*)&Ws[kk * 128 + tc * 4];
            float4 wB = *(const float4*)&Ws[kk * 128 + 64 + tc * 4];
            float4 aA = *(const float4*)&XsT[kk * 132 + tr * 8];
            float4 aB = *(const float4*)&XsT[kk * 132 + tr * 8 + 4];
            float a[8] = {aA.x, aA.y, aA.z, aA.w, aB.x, aB.y, aB.z, aB.w};
            float w[8] = {wA.x, wA.y, wA.z, wA.w, wB.x, wB.y, wB.z, wB.w};
#pragma unroll
            for (int i = 0; i < 8; ++i)
#pragma unroll
                for (int j = 0; j < 8; ++j) acc[i][j] += a[i] * w[j];
        }
    }
    float bA[4] = {bh[tc * 4], bh[tc * 4 + 1], bh[tc * 4 + 2], bh[tc * 4 + 3]};
    float bB[4] = {bh[64 + tc * 4], bh[64 + tc * 4 + 1], bh[64 + tc * 4 + 2], bh[64 + tc * 4 + 3]};
#pragma unroll
    for (int i = 0; i < 8; ++i) {
        int r = row0 + tr * 8 + i;
        if (r >= n_rows) break;
        *(float4*)&out[(size_t)r * 128 + tc * 4] =
            make_float4(acc[i][0] + bA[0], acc[i][1] + bA[1], acc[i][2] + bA[2], acc[i][3] + bA[3]);
        *(float4*)&out[(size_t)r * 128 + 64 + tc * 4] =
            make_float4(acc[i][4] + bB[0], acc[i][5] + bB[1], acc[i][6] + bB[2], acc[i][7] + bB[3]);
    }
}

extern "C" void kernel_launch(void* const* d_in, const int* in_sizes, int n_in,
                              void* d_out, int out_size, void* d_ws, size_t ws_size,
                              hipStream_t stream) {
    const float* x  = (const float*)d_in[0];
    const int*   ei = (const int*)d_in[1];
    const float* ew = (const float*)d_in[2];
    const float* W1 = (const float*)d_in[3];
    const float* b1 = (const float*)d_in[4];
    const float* W2 = (const float*)d_in[5];
    const float* b2 = (const float*)d_in[6];
    const float* W3 = (const float*)d_in[7];
    const float* b3 = (const float*)d_in[8];
    const float* W4 = (const float*)d_in[9];
    const float* b4 = (const float*)d_in[10];
    const float* Wh = (const float*)d_in[11];
    const float* bh = (const float*)d_in[12];

    const int E = in_sizes[2];          // 800000
    const int N = in_sizes[0] / 128;    // 50000
    const int* src = ei;
    const int* dst = ei + E;

    char* p = (char*)d_ws;
    float*          cat     = (float*)p;          p += (size_t)N * 256 * 4;
    unsigned short* hb      = (unsigned short*)p; p += (size_t)N * 64 * 2;
    float*          deg     = (float*)p;          p += (size_t)N * 4;   // deg+cnt one memset
    int*            cnt     = (int*)p;            p += (size_t)N * 4;
    float*          dinv    = (float*)p;          p += (size_t)N * 4;
    int*            row_ptr = (int*)p;            p += (size_t)(N + 1) * 4;
    int*            cursor  = (int*)p;            p += (size_t)N * 4;
    int*            e_src   = (int*)p;            p += (size_t)E * 4;
    float*          e_w     = (float*)p;          p += (size_t)E * 4;
    float*          e_wn    = (float*)p;          p += (size_t)E * 4;
    float* out = (float*)d_out;

    int eb   = (E + 255) / 256;
    int nb   = (N + 255) / 256;
    int nb16 = (N * 16 + 255) / 256;
    int gb   = (N + 127) / 128;

    // ---- CSR build ----
    hipMemsetAsync(deg, 0, (size_t)N * 2 * 4, stream);
    histo_kernel<<<eb, 256, 0, stream>>>(dst, ew, deg, cnt, E);
    dinv_kernel<<<nb, 256, 0, stream>>>(deg, dinv, N);
    scan_kernel<<<1, 1024, 0, stream>>>(cnt, row_ptr, cursor, N);
    fill_kernel<<<eb, 256, 0, stream>>>(src, dst, ew, dinv, cursor, e_src, e_w, e_wn, E);

    // ---- layer 1 (no norm) ----
    gemm_hid<<<gb, 256, 0, stream>>>(x, 128, 128, W1, hb, N);
    gather_plain<<<nb16, 256, 0, stream>>>(row_ptr, e_src, e_w, hb, b1, cat, N);

    // ---- layers 2-4 (normalized) ----
    const float* Wl[3] = {W2, W3, W4};
    const float* bl[3] = {b2, b3, b4};
    for (int l = 1; l < 4; ++l) {
        gemm_hid<<<gb, 256, 0, stream>>>(cat + (size_t)(l - 1) * 64, 256, 64, Wl[l - 1], hb, N);
        gather_norm<<<nb16, 256, 0, stream>>>(row_ptr, e_src, e_wn, hb, dinv,
                                              bl[l - 1], cat, l * 64, N);
    }

    // ---- final projection ----
    gemm_out<<<gb, 256, 0, stream>>>(cat, Wh, bh, out, N);
}

// Round 4
// 395.286 us; speedup vs baseline: 7.5795x; 1.2501x over previous
//
#include <hip/hip_runtime.h>
#include <hip/hip_bf16.h>

#define NEG_SLOP 0.2f

__device__ __forceinline__ float lrelu(float v) { return v > 0.0f ? v : NEG_SLOP * v; }

__device__ __forceinline__ float bf2f(unsigned short u) {
    union { unsigned int i; float f; } c; c.i = ((unsigned int)u) << 16; return c.f;
}
__device__ __forceinline__ unsigned short f2bf(float f) {
    union { float f; unsigned int i; } c; c.f = f;
    unsigned int r = c.i + 0x7FFF + ((c.i >> 16) & 1);  // round-nearest-even
    return (unsigned short)(r >> 16);
}

// ---------------- CSR build ----------------
__global__ void histo_kernel(const int* __restrict__ dst, const float* __restrict__ ew,
                             float* __restrict__ deg, int* __restrict__ cnt, int n_edges) {
    int e = blockIdx.x * 256 + threadIdx.x;
    if (e >= n_edges) return;
    int d = dst[e];
    atomicAdd(&deg[d], ew[e]);
    atomicAdd(&cnt[d], 1);
}

__global__ void dinv_kernel(const float* __restrict__ deg, float* __restrict__ dinv, int n) {
    int i = blockIdx.x * 256 + threadIdx.x;
    if (i >= n) return;
    dinv[i] = rsqrtf(deg[i] + 1.0f);
}

// ---- 3-phase device-wide exclusive scan of cnt (1024 elems / block) ----
__global__ void scan1_kernel(const int* __restrict__ cnt, int* __restrict__ pre,
                             int* __restrict__ bsum, int n) {
    __shared__ int s[256];
    int t = threadIdx.x;
    int base = blockIdx.x * 1024 + t * 4;
    int4 c = make_int4(0, 0, 0, 0);
    if (base + 3 < n) c = *(const int4*)&cnt[base];
    else {
        int tmp[4] = {0, 0, 0, 0};
        for (int j = 0; j < 4; ++j) if (base + j < n) tmp[j] = cnt[base + j];
        c.x = tmp[0]; c.y = tmp[1]; c.z = tmp[2]; c.w = tmp[3];
    }
    int tsum = c.x + c.y + c.z + c.w;
    s[t] = tsum;
    __syncthreads();
    for (int off = 1; off < 256; off <<= 1) {
        int v = (t >= off) ? s[t - off] : 0;
        __syncthreads();
        s[t] += v;
        __syncthreads();
    }
    int ex = s[t] - tsum;
    if (t == 255) bsum[blockIdx.x] = s[255];
    int4 o;
    o.x = ex; o.y = ex + c.x; o.z = o.y + c.y; o.w = o.z + c.z;
    if (base + 3 < n) *(int4*)&pre[base] = o;
    else {
        int tmp[4] = {o.x, o.y, o.z, o.w};
        for (int j = 0; j < 4; ++j) if (base + j < n) pre[base + j] = tmp[j];
    }
}

__global__ void scan2_kernel(int* __restrict__ bsum, int nb) {
    __shared__ int s[64];
    int t = threadIdx.x;
    int v = (t < nb) ? bsum[t] : 0;
    s[t] = v;
    __syncthreads();
    for (int off = 1; off < 64; off <<= 1) {
        int u = (t >= off) ? s[t - off] : 0;
        __syncthreads();
        s[t] += u;
        __syncthreads();
    }
    if (t < nb) bsum[t] = s[t] - v;  // exclusive block offsets
}

__global__ void scan3_kernel(int* __restrict__ rp, int* __restrict__ cursor,
                             const int* __restrict__ bsum, int n, int n_edges) {
    int t = blockIdx.x * 256 + threadIdx.x;
    int base = t * 4;
    if (base >= n) {
        if (base == ((n + 3) & ~3)) rp[n] = n_edges;  // one thread writes the tail
        return;
    }
    int boff = bsum[base >> 10];
    if (base + 3 < n) {
        int4 v = *(const int4*)&rp[base];
        v.x += boff; v.y += boff; v.z += boff; v.w += boff;
        *(int4*)&rp[base] = v;
        *(int4*)&cursor[base] = v;
    } else {
        for (int j = 0; j < 4 && base + j < n; ++j) {
            int v = rp[base + j] + boff;
            rp[base + j] = v;
            cursor[base + j] = v;
        }
        rp[n] = n_edges;
    }
}

__global__ void fill_kernel(const int* __restrict__ src, const int* __restrict__ dst,
                            const float* __restrict__ ew, const float* __restrict__ dinv,
                            int* __restrict__ cursor, int* __restrict__ e_src,
                            float* __restrict__ e_w, float* __restrict__ e_wn, int n_edges) {
    int e = blockIdx.x * 256 + threadIdx.x;
    if (e >= n_edges) return;
    int s = src[e], d = dst[e];
    float w = ew[e];
    int pos = atomicAdd(&cursor[d], 1);
    e_src[pos] = s;
    e_w[pos] = w;
    e_wn[pos] = w * dinv[s] * dinv[d];
}

// ---------------- gathers (hW in bf16) ----------------
__global__ void gather_plain(const int* __restrict__ rp, const int* __restrict__ es,
                             const float* __restrict__ ewt, const unsigned short* __restrict__ hb,
                             const float* __restrict__ b, float* __restrict__ cat, int n) {
    int t = blockIdx.x * 256 + threadIdx.x;
    int node = t >> 4;
    if (node >= n) return;
    int f0 = (t & 15) * 4;
    int lo = rp[node], hi = rp[node + 1];
    float a0 = 0.f, a1 = 0.f, a2 = 0.f, a3 = 0.f;
    for (int k = lo; k < hi; ++k) {
        int s = es[k];
        float w = ewt[k];
        ushort4 u = *(const ushort4*)&hb[(size_t)s * 64 + f0];
        a0 += w * bf2f(u.x); a1 += w * bf2f(u.y);
        a2 += w * bf2f(u.z); a3 += w * bf2f(u.w);
    }
    a0 = lrelu(a0 + b[f0 + 0]); a1 = lrelu(a1 + b[f0 + 1]);
    a2 = lrelu(a2 + b[f0 + 2]); a3 = lrelu(a3 + b[f0 + 3]);
    *(float4*)&cat[(size_t)node * 256 + f0] = make_float4(a0, a1, a2, a3);
}

__global__ void gather_norm(const int* __restrict__ rp, const int* __restrict__ es,
                            const float* __restrict__ ewn, const unsigned short* __restrict__ hb,
                            const float* __restrict__ dinv, const float* __restrict__ b,
                            float* __restrict__ cat, int col_off, int n) {
    int t = blockIdx.x * 256 + threadIdx.x;
    int node = t >> 4;
    if (node >= n) return;
    int f0 = (t & 15) * 4;
    int lo = rp[node], hi = rp[node + 1];
    float a0 = 0.f, a1 = 0.f, a2 = 0.f, a3 = 0.f;
    for (int k = lo; k < hi; ++k) {
        int s = es[k];
        float w = ewn[k];
        ushort4 u = *(const ushort4*)&hb[(size_t)s * 64 + f0];
        a0 += w * bf2f(u.x); a1 += w * bf2f(u.y);
        a2 += w * bf2f(u.z); a3 += w * bf2f(u.w);
    }
    float di = dinv[node];
    float self = di * di;
    ushort4 h = *(const ushort4*)&hb[(size_t)node * 64 + f0];
    a0 = lrelu(a0 + self * bf2f(h.x) + b[f0 + 0]);
    a1 = lrelu(a1 + self * bf2f(h.y) + b[f0 + 1]);
    a2 = lrelu(a2 + self * bf2f(h.z) + b[f0 + 2]);
    a3 = lrelu(a3 + self * bf2f(h.w) + b[f0 + 3]);
    *(float4*)&cat[(size_t)node * 256 + col_off + f0] = make_float4(a0, a1, a2, a3);
}

// ---------------- skinny GEMM: [N x K] @ [K x 64] -> bf16 hW ----------------
__global__ __launch_bounds__(256) void gemm_hid(
    const float* __restrict__ in, int in_stride, int K,
    const float* __restrict__ W, unsigned short* __restrict__ outb, int n_rows) {
    __shared__ float Ws[64 * 64];
    __shared__ float XsT[64 * 132];   // [k][row], padded row-dim 132
    const int tid = threadIdx.x;
    const int tc = tid & 15, tr = tid >> 4;
    const int row0 = blockIdx.x * 128;
    float acc[8][4] = {};
    for (int kc = 0; kc < K; kc += 64) {
        __syncthreads();
        for (int i = tid; i < 64 * 64; i += 256) Ws[i] = W[kc * 64 + i];
        {
            int k = tid & 63, rq = tid >> 6;
            for (int i = 0; i < 32; ++i) {
                int r = rq * 32 + i;
                int rr = row0 + r; if (rr >= n_rows) rr = n_rows - 1;
                XsT[k * 132 + r] = in[(size_t)rr * in_stride + kc + k];
            }
        }
        __syncthreads();
        for (int kk = 0; kk < 64; ++kk) {
            float4 w4 = *(const float4*)&Ws[kk * 64 + tc * 4];
            float4 aA = *(const float4*)&XsT[kk * 132 + tr * 8];
            float4 aB = *(const float4*)&XsT[kk * 132 + tr * 8 + 4];
            float a[8] = {aA.x, aA.y, aA.z, aA.w, aB.x, aB.y, aB.z, aB.w};
#pragma unroll
            for (int i = 0; i < 8; ++i) {
                acc[i][0] += a[i] * w4.x; acc[i][1] += a[i] * w4.y;
                acc[i][2] += a[i] * w4.z; acc[i][3] += a[i] * w4.w;
            }
        }
    }
#pragma unroll
    for (int i = 0; i < 8; ++i) {
        int r = row0 + tr * 8 + i;
        if (r >= n_rows) break;
        ushort4 o;
        o.x = f2bf(acc[i][0]); o.y = f2bf(acc[i][1]);
        o.z = f2bf(acc[i][2]); o.w = f2bf(acc[i][3]);
        *(ushort4*)&outb[(size_t)r * 64 + tc * 4] = o;
    }
}

// ---------------- final GEMM: [N x 256] @ [256 x 128] + bh ----------------
__global__ __launch_bounds__(256) void gemm_out(
    const float* __restrict__ cat, const float* __restrict__ Wh,
    const float* __restrict__ bh, float* __restrict__ out, int n_rows) {
    __shared__ float Ws[64 * 128];
    __shared__ float XsT[64 * 132];
    const int tid = threadIdx.x;
    const int tc = tid & 15, tr = tid >> 4;
    const int row0 = blockIdx.x * 128;
    float acc[8][8] = {};
    for (int kc = 0; kc < 256; kc += 64) {
        __syncthreads();
        for (int i = tid; i < 64 * 128; i += 256) Ws[i] = Wh[kc * 128 + i];
        {
            int k = tid & 63, rq = tid >> 6;
            for (int i = 0; i < 32; ++i) {
                int r = rq * 32 + i;
                int rr = row0 + r; if (rr >= n_rows) rr = n_rows - 1;
                XsT[k * 132 + r] = cat[(size_t)rr * 256 + kc + k];
            }
        }
        __syncthreads();
        for (int kk = 0; kk < 64; ++kk) {
            float4 wA = *(const float4*)&Ws[kk * 128 + tc * 4];
            float4 wB = *(const float4*)&Ws[kk * 128 + 64 + tc * 4];
            float4 aA = *(const float4*)&XsT[kk * 132 + tr * 8];
            float4 aB = *(const float4*)&XsT[kk * 132 + tr * 8 + 4];
            float a[8] = {aA.x, aA.y, aA.z, aA.w, aB.x, aB.y, aB.z, aB.w};
            float w[8] = {wA.x, wA.y, wA.z, wA.w, wB.x, wB.y, wB.z, wB.w};
#pragma unroll
            for (int i = 0; i < 8; ++i)
#pragma unroll
                for (int j = 0; j < 8; ++j) acc[i][j] += a[i] * w[j];
        }
    }
    float bA[4] = {bh[tc * 4], bh[tc * 4 + 1], bh[tc * 4 + 2], bh[tc * 4 + 3]};
    float bB[4] = {bh[64 + tc * 4], bh[64 + tc * 4 + 1], bh[64 + tc * 4 + 2], bh[64 + tc * 4 + 3]};
#pragma unroll
    for (int i = 0; i < 8; ++i) {
        int r = row0 + tr * 8 + i;
        if (r >= n_rows) break;
        *(float4*)&out[(size_t)r * 128 + tc * 4] =
            make_float4(acc[i][0] + bA[0], acc[i][1] + bA[1], acc[i][2] + bA[2], acc[i][3] + bA[3]);
        *(float4*)&out[(size_t)r * 128 + 64 + tc * 4] =
            make_float4(acc[i][4] + bB[0], acc[i][5] + bB[1], acc[i][6] + bB[2], acc[i][7] + bB[3]);
    }
}

extern "C" void kernel_launch(void* const* d_in, const int* in_sizes, int n_in,
                              void* d_out, int out_size, void* d_ws, size_t ws_size,
                              hipStream_t stream) {
    const float* x  = (const float*)d_in[0];
    const int*   ei = (const int*)d_in[1];
    const float* ew = (const float*)d_in[2];
    const float* W1 = (const float*)d_in[3];
    const float* b1 = (const float*)d_in[4];
    const float* W2 = (const float*)d_in[5];
    const float* b2 = (const float*)d_in[6];
    const float* W3 = (const float*)d_in[7];
    const float* b3 = (const float*)d_in[8];
    const float* W4 = (const float*)d_in[9];
    const float* b4 = (const float*)d_in[10];
    const float* Wh = (const float*)d_in[11];
    const float* bh = (const float*)d_in[12];

    const int E = in_sizes[2];          // 800000
    const int N = in_sizes[0] / 128;    // 50000
    const int* src = ei;
    const int* dst = ei + E;

    char* p = (char*)d_ws;
    float*          cat     = (float*)p;          p += (size_t)N * 256 * 4;
    unsigned short* hb      = (unsigned short*)p; p += (size_t)N * 64 * 2;
    float*          deg     = (float*)p;          p += (size_t)N * 4;   // deg+cnt one memset
    int*            cnt     = (int*)p;            p += (size_t)N * 4;
    float*          dinv    = (float*)p;          p += (size_t)N * 4;
    int*            row_ptr = (int*)p;            p += (size_t)(N + 4) * 4;  // padded: keep cursor 16B-aligned
    int*            cursor  = (int*)p;            p += (size_t)N * 4;
    int*            bsum    = (int*)p;            p += (size_t)64 * 4;
    int*            e_src   = (int*)p;            p += (size_t)E * 4;
    float*          e_w     = (float*)p;          p += (size_t)E * 4;
    float*          e_wn    = (float*)p;          p += (size_t)E * 4;
    float* out = (float*)d_out;

    int eb   = (E + 255) / 256;
    int nb   = (N + 255) / 256;
    int nb16 = (N * 16 + 255) / 256;
    int gb   = (N + 127) / 128;
    int sb   = (N + 1023) / 1024;       // scan blocks (1024 elems each), must be <= 64
    int s3b  = ((N + 3) / 4 + 256) / 256;  // scan3: covers n/4 threads + tail writer

    // ---- CSR build ----
    hipMemsetAsync(deg, 0, (size_t)N * 2 * 4, stream);
    histo_kernel<<<eb, 256, 0, stream>>>(dst, ew, deg, cnt, E);
    dinv_kernel<<<nb, 256, 0, stream>>>(deg, dinv, N);
    scan1_kernel<<<sb, 256, 0, stream>>>(cnt, row_ptr, bsum, N);
    scan2_kernel<<<1, 64, 0, stream>>>(bsum, sb);
    scan3_kernel<<<s3b, 256, 0, stream>>>(row_ptr, cursor, bsum, N, E);
    fill_kernel<<<eb, 256, 0, stream>>>(src, dst, ew, dinv, cursor, e_src, e_w, e_wn, E);

    // ---- layer 1 (no norm) ----
    gemm_hid<<<gb, 256, 0, stream>>>(x, 128, 128, W1, hb, N);
    gather_plain<<<nb16, 256, 0, stream>>>(row_ptr, e_src, e_w, hb, b1, cat, N);

    // ---- layers 2-4 (normalized) ----
    const float* Wl[3] = {W2, W3, W4};
    const float* bl[3] = {b2, b3, b4};
    for (int l = 1; l < 4; ++l) {
        gemm_hid<<<gb, 256, 0, stream>>>(cat + (size_t)(l - 1) * 64, 256, 64, Wl[l - 1], hb, N);
        gather_norm<<<nb16, 256, 0, stream>>>(row_ptr, e_src, e_wn, hb, dinv,
                                              bl[l - 1], cat, l * 64, N);
    }

    // ---- final projection ----
    gemm_out<<<gb, 256, 0, stream>>>(cat, Wh, bh, out, N);
}

// Round 5
// 331.628 us; speedup vs baseline: 9.0344x; 1.1920x over previous
//
#include <hip/hip_runtime.h>
#include <hip/hip_bf16.h>

#define NEG_SLOP 0.2f
typedef unsigned long long ull;

__device__ __forceinline__ float lrelu(float v) { return v > 0.0f ? v : NEG_SLOP * v; }

__device__ __forceinline__ float bf2f(unsigned short u) {
    union { unsigned int i; float f; } c; c.i = ((unsigned int)u) << 16; return c.f;
}
__device__ __forceinline__ unsigned short f2bf(float f) {
    union { float f; unsigned int i; } c; c.f = f;
    unsigned int r = c.i + 0x7FFF + ((c.i >> 16) & 1);  // round-nearest-even
    return (unsigned short)(r >> 16);
}

// ---------------- histogram: packed (cnt<<40 | fixed-point weight sum), emits rank ----------------
__global__ void histo_kernel(const int* __restrict__ dst, const float* __restrict__ ew,
                             ull* __restrict__ packed, int* __restrict__ rank, int n_edges) {
    int e = blockIdx.x * 256 + threadIdx.x;
    if (e >= n_edges) return;
    int d = dst[e];
    ull delta = (1ULL << 40) | (ull)(ew[e] * 4294967296.0f);
    ull old = atomicAdd(&packed[d], delta);
    rank[e] = (int)(old >> 40);
}

__global__ void dinv_kernel(const ull* __restrict__ packed, float* __restrict__ dinv, int n) {
    int i = blockIdx.x * 256 + threadIdx.x;
    if (i >= n) return;
    float deg = (float)(packed[i] & ((1ULL << 40) - 1)) * (1.0f / 4294967296.0f);
    dinv[i] = rsqrtf(deg + 1.0f);  // +1 self loop
}

// ---- 3-phase device-wide exclusive scan of counts (1024 elems / block) ----
__global__ void scan1_kernel(const ull* __restrict__ packed, int* __restrict__ pre,
                             int* __restrict__ bsum, int n) {
    __shared__ int s[256];
    int t = threadIdx.x;
    int base = blockIdx.x * 1024 + t * 4;
    int c[4];
#pragma unroll
    for (int j = 0; j < 4; ++j) c[j] = (base + j < n) ? (int)(packed[base + j] >> 40) : 0;
    int tsum = c[0] + c[1] + c[2] + c[3];
    s[t] = tsum;
    __syncthreads();
    for (int off = 1; off < 256; off <<= 1) {
        int v = (t >= off) ? s[t - off] : 0;
        __syncthreads();
        s[t] += v;
        __syncthreads();
    }
    int ex = s[t] - tsum;
    if (t == 255) bsum[blockIdx.x] = s[255];
    int o[4];
    o[0] = ex; o[1] = ex + c[0]; o[2] = o[1] + c[1]; o[3] = o[2] + c[2];
    if (base + 3 < n) *(int4*)&pre[base] = make_int4(o[0], o[1], o[2], o[3]);
    else {
        for (int j = 0; j < 4; ++j) if (base + j < n) pre[base + j] = o[j];
    }
}

__global__ void scan2_kernel(int* __restrict__ bsum, int nb) {
    __shared__ int s[64];
    int t = threadIdx.x;
    int v = (t < nb) ? bsum[t] : 0;
    s[t] = v;
    __syncthreads();
    for (int off = 1; off < 64; off <<= 1) {
        int u = (t >= off) ? s[t - off] : 0;
        __syncthreads();
        s[t] += u;
        __syncthreads();
    }
    if (t < nb) bsum[t] = s[t] - v;
}

__global__ void scan3_kernel(int* __restrict__ rp, const int* __restrict__ bsum,
                             int n, int n_edges) {
    int t = blockIdx.x * 256 + threadIdx.x;
    int base = t * 4;
    if (base >= n) {
        if (base == ((n + 3) & ~3)) rp[n] = n_edges;
        return;
    }
    int boff = bsum[base >> 10];
    if (base + 3 < n) {
        int4 v = *(const int4*)&rp[base];
        v.x += boff; v.y += boff; v.z += boff; v.w += boff;
        *(int4*)&rp[base] = v;
    } else {
        for (int j = 0; j < 4 && base + j < n; ++j) rp[base + j] += boff;
        rp[n] = n_edges;
    }
}

// ---------------- CSR fill: atomic-free (rank-based placement) ----------------
__global__ void fill_kernel(const int* __restrict__ src, const int* __restrict__ dst,
                            const float* __restrict__ ew, const int* __restrict__ rank,
                            const int* __restrict__ rp, const float* __restrict__ dinv,
                            int2* __restrict__ e_sw, int2* __restrict__ e_swn, int n_edges) {
    int e = blockIdx.x * 256 + threadIdx.x;
    if (e >= n_edges) return;
    int s = src[e], d = dst[e];
    float w = ew[e];
    int pos = rp[d] + rank[e];
    e_sw[pos] = make_int2(s, __float_as_int(w));
    e_swn[pos] = make_int2(s, __float_as_int(w * dinv[s] * dinv[d]));
}

// ---------------- gathers: one wave per node, 4 edges x 16 feature-lanes ----------------
__global__ void gather_plain(const int* __restrict__ rp, const int2* __restrict__ e_sw,
                             const unsigned short* __restrict__ hb,
                             const float* __restrict__ b, float* __restrict__ cat, int n) {
    int node = (blockIdx.x * 256 + threadIdx.x) >> 6;
    if (node >= n) return;
    int lane = threadIdx.x & 63;
    int eg = lane >> 4;
    int f0 = (lane & 15) * 4;
    int lo = rp[node], hi = rp[node + 1];
    float a0 = 0.f, a1 = 0.f, a2 = 0.f, a3 = 0.f;
    for (int k = lo + eg; k < hi; k += 4) {
        int2 p = e_sw[k];
        float w = __int_as_float(p.y);
        ushort4 u = *(const ushort4*)&hb[(size_t)p.x * 64 + f0];
        a0 += w * bf2f(u.x); a1 += w * bf2f(u.y);
        a2 += w * bf2f(u.z); a3 += w * bf2f(u.w);
    }
    a0 += __shfl_xor(a0, 16, 64); a0 += __shfl_xor(a0, 32, 64);
    a1 += __shfl_xor(a1, 16, 64); a1 += __shfl_xor(a1, 32, 64);
    a2 += __shfl_xor(a2, 16, 64); a2 += __shfl_xor(a2, 32, 64);
    a3 += __shfl_xor(a3, 16, 64); a3 += __shfl_xor(a3, 32, 64);
    if (eg == 0) {
        a0 = lrelu(a0 + b[f0 + 0]); a1 = lrelu(a1 + b[f0 + 1]);
        a2 = lrelu(a2 + b[f0 + 2]); a3 = lrelu(a3 + b[f0 + 3]);
        *(float4*)&cat[(size_t)node * 256 + f0] = make_float4(a0, a1, a2, a3);
    }
}

__global__ void gather_norm(const int* __restrict__ rp, const int2* __restrict__ e_swn,
                            const unsigned short* __restrict__ hb,
                            const float* __restrict__ dinv, const float* __restrict__ b,
                            float* __restrict__ cat, int col_off, int n) {
    int node = (blockIdx.x * 256 + threadIdx.x) >> 6;
    if (node >= n) return;
    int lane = threadIdx.x & 63;
    int eg = lane >> 4;
    int f0 = (lane & 15) * 4;
    int lo = rp[node], hi = rp[node + 1];
    float a0 = 0.f, a1 = 0.f, a2 = 0.f, a3 = 0.f;
    for (int k = lo + eg; k < hi; k += 4) {
        int2 p = e_swn[k];
        float w = __int_as_float(p.y);
        ushort4 u = *(const ushort4*)&hb[(size_t)p.x * 64 + f0];
        a0 += w * bf2f(u.x); a1 += w * bf2f(u.y);
        a2 += w * bf2f(u.z); a3 += w * bf2f(u.w);
    }
    a0 += __shfl_xor(a0, 16, 64); a0 += __shfl_xor(a0, 32, 64);
    a1 += __shfl_xor(a1, 16, 64); a1 += __shfl_xor(a1, 32, 64);
    a2 += __shfl_xor(a2, 16, 64); a2 += __shfl_xor(a2, 32, 64);
    a3 += __shfl_xor(a3, 16, 64); a3 += __shfl_xor(a3, 32, 64);
    if (eg == 0) {
        float di = dinv[node];
        float self = di * di;
        ushort4 h = *(const ushort4*)&hb[(size_t)node * 64 + f0];
        a0 = lrelu(a0 + self * bf2f(h.x) + b[f0 + 0]);
        a1 = lrelu(a1 + self * bf2f(h.y) + b[f0 + 1]);
        a2 = lrelu(a2 + self * bf2f(h.z) + b[f0 + 2]);
        a3 = lrelu(a3 + self * bf2f(h.w) + b[f0 + 3]);
        *(float4*)&cat[(size_t)node * 256 + col_off + f0] = make_float4(a0, a1, a2, a3);
    }
}

// ---------------- skinny GEMM: [N x K] @ [K x 64] -> bf16 hW ----------------
__global__ __launch_bounds__(256) void gemm_hid(
    const float* __restrict__ in, int in_stride, int K,
    const float* __restrict__ W, unsigned short* __restrict__ outb, int n_rows) {
    __shared__ float Ws[64 * 64];
    __shared__ float XsT[64 * 132];   // [k][row], padded row-dim 132
    const int tid = threadIdx.x;
    const int tc = tid & 15, tr = tid >> 4;
    const int row0 = blockIdx.x * 128;
    float acc[8][4] = {};
    for (int kc = 0; kc < K; kc += 64) {
        __syncthreads();
        for (int i = tid; i < 64 * 64; i += 256) Ws[i] = W[kc * 64 + i];
        {
            int k = tid & 63, rq = tid >> 6;
            for (int i = 0; i < 32; ++i) {
                int r = rq * 32 + i;
                int rr = row0 + r; if (rr >= n_rows) rr = n_rows - 1;
                XsT[k * 132 + r] = in[(size_t)rr * in_stride + kc + k];
            }
        }
        __syncthreads();
        for (int kk = 0; kk < 64; ++kk) {
            float4 w4 = *(const float4*)&Ws[kk * 64 + tc * 4];
            float4 aA = *(const float4*)&XsT[kk * 132 + tr * 8];
            float4 aB = *(const float4*)&XsT[kk * 132 + tr * 8 + 4];
            float a[8] = {aA.x, aA.y, aA.z, aA.w, aB.x, aB.y, aB.z, aB.w};
#pragma unroll
            for (int i = 0; i < 8; ++i) {
                acc[i][0] += a[i] * w4.x; acc[i][1] += a[i] * w4.y;
                acc[i][2] += a[i] * w4.z; acc[i][3] += a[i] * w4.w;
            }
        }
    }
#pragma unroll
    for (int i = 0; i < 8; ++i) {
        int r = row0 + tr * 8 + i;
        if (r >= n_rows) break;
        ushort4 o;
        o.x = f2bf(acc[i][0]); o.y = f2bf(acc[i][1]);
        o.z = f2bf(acc[i][2]); o.w = f2bf(acc[i][3]);
        *(ushort4*)&outb[(size_t)r * 64 + tc * 4] = o;
    }
}

// ---------------- final GEMM: [N x 256] @ [256 x 128] + bh ----------------
__global__ __launch_bounds__(256) void gemm_out(
    const float* __restrict__ cat, const float* __restrict__ Wh,
    const float* __restrict__ bh, float* __restrict__ out, int n_rows) {
    __shared__ float Ws[64 * 128];
    __shared__ float XsT[64 * 132];
    const int tid = threadIdx.x;
    const int tc = tid & 15, tr = tid >> 4;
    const int row0 = blockIdx.x * 128;
    float acc[8][8] = {};
    for (int kc = 0; kc < 256; kc += 64) {
        __syncthreads();
        for (int i = tid; i < 64 * 128; i += 256) Ws[i] = Wh[kc * 128 + i];
        {
            int k = tid & 63, rq = tid >> 6;
            for (int i = 0; i < 32; ++i) {
                int r = rq * 32 + i;
                int rr = row0 + r; if (rr >= n_rows) rr = n_rows - 1;
                XsT[k * 132 + r] = cat[(size_t)rr * 256 + kc + k];
            }
        }
        __syncthreads();
        for (int kk = 0; kk < 64; ++kk) {
            float4 wA = *(const float4*)&Ws[kk * 128 + tc * 4];
            float4 wB = *(const float4*)&Ws[kk * 128 + 64 + tc * 4];
            float4 aA = *(const float4*)&XsT[kk * 132 + tr * 8];
            float4 aB = *(const float4*)&XsT[kk * 132 + tr * 8 + 4];
            float a[8] = {aA.x, aA.y, aA.z, aA.w, aB.x, aB.y, aB.z, aB.w};
            float w[8] = {wA.x, wA.y, wA.z, wA.w, wB.x, wB.y, wB.z, wB.w};
#pragma unroll
            for (int i = 0; i < 8; ++i)
#pragma unroll
                for (int j = 0; j < 8; ++j) acc[i][j] += a[i] * w[j];
        }
    }
    float bA[4] = {bh[tc * 4], bh[tc * 4 + 1], bh[tc * 4 + 2], bh[tc * 4 + 3]};
    float bB[4] = {bh[64 + tc * 4], bh[64 + tc * 4 + 1], bh[64 + tc * 4 + 2], bh[64 + tc * 4 + 3]};
#pragma unroll
    for (int i = 0; i < 8; ++i) {
        int r = row0 + tr * 8 + i;
        if (r >= n_rows) break;
        *(float4*)&out[(size_t)r * 128 + tc * 4] =
            make_float4(acc[i][0] + bA[0], acc[i][1] + bA[1], acc[i][2] + bA[2], acc[i][3] + bA[3]);
        *(float4*)&out[(size_t)r * 128 + 64 + tc * 4] =
            make_float4(acc[i][4] + bB[0], acc[i][5] + bB[1], acc[i][6] + bB[2], acc[i][7] + bB[3]);
    }
}

extern "C" void kernel_launch(void* const* d_in, const int* in_sizes, int n_in,
                              void* d_out, int out_size, void* d_ws, size_t ws_size,
                              hipStream_t stream) {
    const float* x  = (const float*)d_in[0];
    const int*   ei = (const int*)d_in[1];
    const float* ew = (const float*)d_in[2];
    const float* W1 = (const float*)d_in[3];
    const float* b1 = (const float*)d_in[4];
    const float* W2 = (const float*)d_in[5];
    const float* b2 = (const float*)d_in[6];
    const float* W3 = (const float*)d_in[7];
    const float* b3 = (const float*)d_in[8];
    const float* W4 = (const float*)d_in[9];
    const float* b4 = (const float*)d_in[10];
    const float* Wh = (const float*)d_in[11];
    const float* bh = (const float*)d_in[12];

    const int E = in_sizes[2];          // 800000
    const int N = in_sizes[0] / 128;    // 50000
    const int* src = ei;
    const int* dst = ei + E;

    char* p = (char*)d_ws;
    float*          cat     = (float*)p;          p += (size_t)N * 256 * 4;
    unsigned short* hb      = (unsigned short*)p; p += (size_t)N * 64 * 2;
    ull*            packed  = (ull*)p;            p += (size_t)N * 8;
    float*          dinv    = (float*)p;          p += (size_t)N * 4;
    int*            row_ptr = (int*)p;            p += (size_t)(N + 4) * 4;
    int*            bsum    = (int*)p;            p += (size_t)64 * 4;
    int*            rank    = (int*)p;            p += (size_t)E * 4;
    int2*           e_sw    = (int2*)p;           p += (size_t)E * 8;
    int2*           e_swn   = (int2*)p;           p += (size_t)E * 8;
    float* out = (float*)d_out;

    int eb   = (E + 255) / 256;
    int nb   = (N + 255) / 256;
    int nb64 = (N * 64 + 255) / 256;     // wave per node
    int gb   = (N + 127) / 128;
    int sb   = (N + 1023) / 1024;        // <= 64
    int s3b  = ((N + 3) / 4 + 256) / 256;

    // ---- CSR build ----
    hipMemsetAsync(packed, 0, (size_t)N * 8, stream);
    histo_kernel<<<eb, 256, 0, stream>>>(dst, ew, packed, rank, E);
    dinv_kernel<<<nb, 256, 0, stream>>>(packed, dinv, N);
    scan1_kernel<<<sb, 256, 0, stream>>>(packed, row_ptr, bsum, N);
    scan2_kernel<<<1, 64, 0, stream>>>(bsum, sb);
    scan3_kernel<<<s3b, 256, 0, stream>>>(row_ptr, bsum, N, E);
    fill_kernel<<<eb, 256, 0, stream>>>(src, dst, ew, rank, row_ptr, dinv, e_sw, e_swn, E);

    // ---- layer 1 (no norm) ----
    gemm_hid<<<gb, 256, 0, stream>>>(x, 128, 128, W1, hb, N);
    gather_plain<<<nb64, 256, 0, stream>>>(row_ptr, e_sw, hb, b1, cat, N);

    // ---- layers 2-4 (normalized) ----
    const float* Wl[3] = {W2, W3, W4};
    const float* bl[3] = {b2, b3, b4};
    for (int l = 1; l < 4; ++l) {
        gemm_hid<<<gb, 256, 0, stream>>>(cat + (size_t)(l - 1) * 64, 256, 64, Wl[l - 1], hb, N);
        gather_norm<<<nb64, 256, 0, stream>>>(row_ptr, e_swn, hb, dinv,
                                              bl[l - 1], cat, l * 64, N);
    }

    // ---- final projection ----
    gemm_out<<<gb, 256, 0, stream>>>(cat, Wh, bh, out, N);
}

// Round 6
// 294.425 us; speedup vs baseline: 10.1760x; 1.1264x over previous
//
#include <hip/hip_runtime.h>
#include <hip/hip_bf16.h>

#define NEG_SLOP 0.2f
typedef unsigned long long ull;
typedef __attribute__((ext_vector_type(8))) short bf16x8;
typedef __attribute__((ext_vector_type(4))) float f32x4;

__device__ __forceinline__ float lrelu(float v) { return v > 0.0f ? v : NEG_SLOP * v; }

__device__ __forceinline__ float bf2f(unsigned short u) {
    union { unsigned int i; float f; } c; c.i = ((unsigned int)u) << 16; return c.f;
}
__device__ __forceinline__ unsigned short f2bf(float f) {
    union { float f; unsigned int i; } c; c.f = f;
    unsigned int r = c.i + 0x7FFF + ((c.i >> 16) & 1);  // round-nearest-even
    return (unsigned short)(r >> 16);
}

// ---------------- histogram: packed (cnt<<40 | fixed-point weight sum), emits rank ----------------
__global__ void histo_kernel(const int* __restrict__ dst, const float* __restrict__ ew,
                             ull* __restrict__ packed, int* __restrict__ rank, int n_edges) {
    int e = blockIdx.x * 256 + threadIdx.x;
    if (e >= n_edges) return;
    int d = dst[e];
    ull delta = (1ULL << 40) | (ull)(ew[e] * 4294967296.0f);
    ull old = atomicAdd(&packed[d], delta);
    rank[e] = (int)(old >> 40);
}

__global__ void dinv_kernel(const ull* __restrict__ packed, float* __restrict__ dinv, int n) {
    int i = blockIdx.x * 256 + threadIdx.x;
    if (i >= n) return;
    float deg = (float)(packed[i] & ((1ULL << 40) - 1)) * (1.0f / 4294967296.0f);
    dinv[i] = rsqrtf(deg + 1.0f);  // +1 self loop
}

// ---- 3-phase device-wide exclusive scan of counts ----
__global__ void scan1_kernel(const ull* __restrict__ packed, int* __restrict__ pre,
                             int* __restrict__ bsum, int n) {
    __shared__ int s[256];
    int t = threadIdx.x;
    int base = blockIdx.x * 1024 + t * 4;
    int c[4];
#pragma unroll
    for (int j = 0; j < 4; ++j) c[j] = (base + j < n) ? (int)(packed[base + j] >> 40) : 0;
    int tsum = c[0] + c[1] + c[2] + c[3];
    s[t] = tsum;
    __syncthreads();
    for (int off = 1; off < 256; off <<= 1) {
        int v = (t >= off) ? s[t - off] : 0;
        __syncthreads();
        s[t] += v;
        __syncthreads();
    }
    int ex = s[t] - tsum;
    if (t == 255) bsum[blockIdx.x] = s[255];
    int o[4];
    o[0] = ex; o[1] = ex + c[0]; o[2] = o[1] + c[1]; o[3] = o[2] + c[2];
    if (base + 3 < n) *(int4*)&pre[base] = make_int4(o[0], o[1], o[2], o[3]);
    else {
        for (int j = 0; j < 4; ++j) if (base + j < n) pre[base + j] = o[j];
    }
}

__global__ void scan2_kernel(int* __restrict__ bsum, int nb) {
    __shared__ int s[64];
    int t = threadIdx.x;
    int v = (t < nb) ? bsum[t] : 0;
    s[t] = v;
    __syncthreads();
    for (int off = 1; off < 64; off <<= 1) {
        int u = (t >= off) ? s[t - off] : 0;
        __syncthreads();
        s[t] += u;
        __syncthreads();
    }
    if (t < nb) bsum[t] = s[t] - v;
}

__global__ void scan3_kernel(int* __restrict__ rp, const int* __restrict__ bsum,
                             int n, int n_edges) {
    int t = blockIdx.x * 256 + threadIdx.x;
    int base = t * 4;
    if (base >= n) {
        if (base == ((n + 3) & ~3)) rp[n] = n_edges;
        return;
    }
    int boff = bsum[base >> 10];
    if (base + 3 < n) {
        int4 v = *(const int4*)&rp[base];
        v.x += boff; v.y += boff; v.z += boff; v.w += boff;
        *(int4*)&rp[base] = v;
    } else {
        for (int j = 0; j < 4 && base + j < n; ++j) rp[base + j] += boff;
        rp[n] = n_edges;
    }
}

// ---------------- CSR fill: atomic-free (rank-based placement) ----------------
__global__ void fill_kernel(const int* __restrict__ src, const int* __restrict__ dst,
                            const float* __restrict__ ew, const int* __restrict__ rank,
                            const int* __restrict__ rp, const float* __restrict__ dinv,
                            int2* __restrict__ e_sw, int2* __restrict__ e_swn, int n_edges) {
    int e = blockIdx.x * 256 + threadIdx.x;
    if (e >= n_edges) return;
    int s = src[e], d = dst[e];
    float w = ew[e];
    int pos = rp[d] + rank[e];
    e_sw[pos] = make_int2(s, __float_as_int(w));
    e_swn[pos] = make_int2(s, __float_as_int(w * dinv[s] * dinv[d]));
}

// ---------------- gathers: one wave per node, 4 edges x 16 feature-lanes; bf16 cat out ----------------
__global__ void gather_plain(const int* __restrict__ rp, const int2* __restrict__ e_sw,
                             const unsigned short* __restrict__ hb,
                             const float* __restrict__ b, unsigned short* __restrict__ cat, int n) {
    int node = (blockIdx.x * 256 + threadIdx.x) >> 6;
    if (node >= n) return;
    int lane = threadIdx.x & 63;
    int eg = lane >> 4;
    int f0 = (lane & 15) * 4;
    int lo = rp[node], hi = rp[node + 1];
    float a0 = 0.f, a1 = 0.f, a2 = 0.f, a3 = 0.f;
    for (int k = lo + eg; k < hi; k += 4) {
        int2 p = e_sw[k];
        float w = __int_as_float(p.y);
        ushort4 u = *(const ushort4*)&hb[(size_t)p.x * 64 + f0];
        a0 += w * bf2f(u.x); a1 += w * bf2f(u.y);
        a2 += w * bf2f(u.z); a3 += w * bf2f(u.w);
    }
    a0 += __shfl_xor(a0, 16, 64); a0 += __shfl_xor(a0, 32, 64);
    a1 += __shfl_xor(a1, 16, 64); a1 += __shfl_xor(a1, 32, 64);
    a2 += __shfl_xor(a2, 16, 64); a2 += __shfl_xor(a2, 32, 64);
    a3 += __shfl_xor(a3, 16, 64); a3 += __shfl_xor(a3, 32, 64);
    if (eg == 0) {
        ushort4 o;
        o.x = f2bf(lrelu(a0 + b[f0 + 0])); o.y = f2bf(lrelu(a1 + b[f0 + 1]));
        o.z = f2bf(lrelu(a2 + b[f0 + 2])); o.w = f2bf(lrelu(a3 + b[f0 + 3]));
        *(ushort4*)&cat[(size_t)node * 256 + f0] = o;
    }
}

__global__ void gather_norm(const int* __restrict__ rp, const int2* __restrict__ e_swn,
                            const unsigned short* __restrict__ hb,
                            const float* __restrict__ dinv, const float* __restrict__ b,
                            unsigned short* __restrict__ cat, int col_off, int n) {
    int node = (blockIdx.x * 256 + threadIdx.x) >> 6;
    if (node >= n) return;
    int lane = threadIdx.x & 63;
    int eg = lane >> 4;
    int f0 = (lane & 15) * 4;
    int lo = rp[node], hi = rp[node + 1];
    float a0 = 0.f, a1 = 0.f, a2 = 0.f, a3 = 0.f;
    for (int k = lo + eg; k < hi; k += 4) {
        int2 p = e_swn[k];
        float w = __int_as_float(p.y);
        ushort4 u = *(const ushort4*)&hb[(size_t)p.x * 64 + f0];
        a0 += w * bf2f(u.x); a1 += w * bf2f(u.y);
        a2 += w * bf2f(u.z); a3 += w * bf2f(u.w);
    }
    a0 += __shfl_xor(a0, 16, 64); a0 += __shfl_xor(a0, 32, 64);
    a1 += __shfl_xor(a1, 16, 64); a1 += __shfl_xor(a1, 32, 64);
    a2 += __shfl_xor(a2, 16, 64); a2 += __shfl_xor(a2, 32, 64);
    a3 += __shfl_xor(a3, 16, 64); a3 += __shfl_xor(a3, 32, 64);
    if (eg == 0) {
        float di = dinv[node];
        float self = di * di;
        ushort4 h = *(const ushort4*)&hb[(size_t)node * 64 + f0];
        ushort4 o;
        o.x = f2bf(lrelu(a0 + self * bf2f(h.x) + b[f0 + 0]));
        o.y = f2bf(lrelu(a1 + self * bf2f(h.y) + b[f0 + 1]));
        o.z = f2bf(lrelu(a2 + self * bf2f(h.z) + b[f0 + 2]));
        o.w = f2bf(lrelu(a3 + self * bf2f(h.w) + b[f0 + 3]));
        *(ushort4*)&cat[(size_t)node * 256 + col_off + f0] = o;
    }
}

// ---------------- skinny GEMM (fp32 in): [N x 128] @ [128 x 64] -> bf16 hW (layer 1) ----------------
__global__ __launch_bounds__(256) void gemm_hid_f32(
    const float* __restrict__ in, int in_stride, int K,
    const float* __restrict__ W, unsigned short* __restrict__ outb, int n_rows) {
    __shared__ float Ws[64 * 64];
    __shared__ float XsT[64 * 132];
    const int tid = threadIdx.x;
    const int tc = tid & 15, tr = tid >> 4;
    const int row0 = blockIdx.x * 128;
    float acc[8][4] = {};
    for (int kc = 0; kc < K; kc += 64) {
        __syncthreads();
        for (int i = tid; i < 64 * 64; i += 256) Ws[i] = W[kc * 64 + i];
        {
            int k = tid & 63, rq = tid >> 6;
            for (int i = 0; i < 32; ++i) {
                int r = rq * 32 + i;
                int rr = row0 + r; if (rr >= n_rows) rr = n_rows - 1;
                XsT[k * 132 + r] = in[(size_t)rr * in_stride + kc + k];
            }
        }
        __syncthreads();
        for (int kk = 0; kk < 64; ++kk) {
            float4 w4 = *(const float4*)&Ws[kk * 64 + tc * 4];
            float4 aA = *(const float4*)&XsT[kk * 132 + tr * 8];
            float4 aB = *(const float4*)&XsT[kk * 132 + tr * 8 + 4];
            float a[8] = {aA.x, aA.y, aA.z, aA.w, aB.x, aB.y, aB.z, aB.w};
#pragma unroll
            for (int i = 0; i < 8; ++i) {
                acc[i][0] += a[i] * w4.x; acc[i][1] += a[i] * w4.y;
                acc[i][2] += a[i] * w4.z; acc[i][3] += a[i] * w4.w;
            }
        }
    }
#pragma unroll
    for (int i = 0; i < 8; ++i) {
        int r = row0 + tr * 8 + i;
        if (r >= n_rows) break;
        ushort4 o;
        o.x = f2bf(acc[i][0]); o.y = f2bf(acc[i][1]);
        o.z = f2bf(acc[i][2]); o.w = f2bf(acc[i][3]);
        *(ushort4*)&outb[(size_t)r * 64 + tc * 4] = o;
    }
}

// ---------------- skinny GEMM (bf16 in): [N x 64] @ [64 x 64] -> bf16 hW (layers 2-4) ----------------
__global__ __launch_bounds__(256) void gemm_hid_b(
    const unsigned short* __restrict__ in, int in_stride,
    const float* __restrict__ W, unsigned short* __restrict__ outb, int n_rows) {
    __shared__ float Ws[64 * 64];
    __shared__ float XsT[64 * 132];
    const int tid = threadIdx.x;
    const int tc = tid & 15, tr = tid >> 4;
    const int row0 = blockIdx.x * 128;
    float acc[8][4] = {};
    for (int i = tid; i < 64 * 64; i += 256) Ws[i] = W[i];
    {
        int k = tid & 63, rq = tid >> 6;
        for (int i = 0; i < 32; ++i) {
            int r = rq * 32 + i;
            int rr = row0 + r; if (rr >= n_rows) rr = n_rows - 1;
            XsT[k * 132 + r] = bf2f(in[(size_t)rr * in_stride + k]);
        }
    }
    __syncthreads();
    for (int kk = 0; kk < 64; ++kk) {
        float4 w4 = *(const float4*)&Ws[kk * 64 + tc * 4];
        float4 aA = *(const float4*)&XsT[kk * 132 + tr * 8];
        float4 aB = *(const float4*)&XsT[kk * 132 + tr * 8 + 4];
        float a[8] = {aA.x, aA.y, aA.z, aA.w, aB.x, aB.y, aB.z, aB.w};
#pragma unroll
        for (int i = 0; i < 8; ++i) {
            acc[i][0] += a[i] * w4.x; acc[i][1] += a[i] * w4.y;
            acc[i][2] += a[i] * w4.z; acc[i][3] += a[i] * w4.w;
        }
    }
#pragma unroll
    for (int i = 0; i < 8; ++i) {
        int r = row0 + tr * 8 + i;
        if (r >= n_rows) break;
        ushort4 o;
        o.x = f2bf(acc[i][0]); o.y = f2bf(acc[i][1]);
        o.z = f2bf(acc[i][2]); o.w = f2bf(acc[i][3]);
        *(ushort4*)&outb[(size_t)r * 64 + tc * 4] = o;
    }
}

// ---------------- Wh fp32 [256][128] -> WhT bf16 [128][256] ----------------
__global__ void wht_kernel(const float* __restrict__ Wh, unsigned short* __restrict__ wht) {
    int idx = blockIdx.x * 256 + threadIdx.x;
    if (idx >= 256 * 128) return;
    int k = idx >> 7, c = idx & 127;
    wht[(size_t)c * 256 + k] = f2bf(Wh[idx]);
}

// ---------------- final GEMM via MFMA: cat(bf16)[N x 256] @ Wh[256 x 128] + bh ----------------
// 64 rows/block, 4 waves; K chunked by 64; XOR-swizzled LDS (A 8KB + B 16KB).
__global__ __launch_bounds__(256) void gemm_out_mfma(
    const unsigned short* __restrict__ cat, const unsigned short* __restrict__ whT,
    const float* __restrict__ bh, float* __restrict__ out, int n_rows) {
    __shared__ __align__(16) char As[64 * 128];    // [row][k] bf16, swizzled
    __shared__ __align__(16) char Bs[128 * 128];   // [col][k] bf16, swizzled
    const int tid = threadIdx.x;
    const int wid = tid >> 6, lane = tid & 63;
    const int row0 = blockIdx.x * 64;
    const int lrow = lane & 15, kg = lane >> 4;
    f32x4 acc[8] = {};
    for (int kc = 0; kc < 4; ++kc) {
        __syncthreads();
        {   // stage A: 64 rows x 64 k bf16
            int row = tid >> 2, seg = tid & 3;
            int rr = row0 + row; if (rr >= n_rows) rr = n_rows - 1;
            const int4* g = (const int4*)&cat[(size_t)rr * 256 + kc * 64 + seg * 16];
            int4 u0 = g[0], u1 = g[1];
            int sw = (row & 7) << 4;
            int base = row * 128 + seg * 32;
            *(int4*)(As + (base ^ sw)) = u0;
            *(int4*)(As + ((base + 16) ^ sw)) = u1;
        }
        {   // stage B: 128 cols x 64 k bf16
            int c = tid >> 1, seg = tid & 1;
            const int4* g = (const int4*)&whT[(size_t)c * 256 + kc * 64 + seg * 32];
            int sw = (c & 7) << 4;
            int base = c * 128 + seg * 64;
#pragma unroll
            for (int i = 0; i < 4; ++i)
                *(int4*)(Bs + ((base + i * 16) ^ sw)) = g[i];
        }
        __syncthreads();
        int arow = wid * 16 + lrow;
        int asw = (arow & 7) << 4;
#pragma unroll
        for (int ks = 0; ks < 2; ++ks) {
            bf16x8 af = *(bf16x8*)(As + ((arow * 128 + ks * 64 + kg * 16) ^ asw));
#pragma unroll
            for (int cf = 0; cf < 8; ++cf) {
                int c = cf * 16 + lrow;
                bf16x8 bf = *(bf16x8*)(Bs + ((c * 128 + ks * 64 + kg * 16) ^ ((c & 7) << 4)));
                acc[cf] = __builtin_amdgcn_mfma_f32_16x16x32_bf16(af, bf, acc[cf], 0, 0, 0);
            }
        }
    }
    // epilogue: C/D row=(lane>>4)*4+reg, col=lane&15
    int lrow4 = (lane >> 4) * 4;
#pragma unroll
    for (int cf = 0; cf < 8; ++cf) {
        int col = cf * 16 + lrow;
        float bias = bh[col];
#pragma unroll
        for (int reg = 0; reg < 4; ++reg) {
            int r = row0 + wid * 16 + lrow4 + reg;
            if (r < n_rows) out[(size_t)r * 128 + col] = acc[cf][reg] + bias;
        }
    }
}

extern "C" void kernel_launch(void* const* d_in, const int* in_sizes, int n_in,
                              void* d_out, int out_size, void* d_ws, size_t ws_size,
                              hipStream_t stream) {
    const float* x  = (const float*)d_in[0];
    const int*   ei = (const int*)d_in[1];
    const float* ew = (const float*)d_in[2];
    const float* W1 = (const float*)d_in[3];
    const float* b1 = (const float*)d_in[4];
    const float* W2 = (const float*)d_in[5];
    const float* b2 = (const float*)d_in[6];
    const float* W3 = (const float*)d_in[7];
    const float* b3 = (const float*)d_in[8];
    const float* W4 = (const float*)d_in[9];
    const float* b4 = (const float*)d_in[10];
    const float* Wh = (const float*)d_in[11];
    const float* bh = (const float*)d_in[12];

    const int E = in_sizes[2];          // 800000
    const int N = in_sizes[0] / 128;    // 50000
    const int* src = ei;
    const int* dst = ei + E;

    char* p = (char*)d_ws;
    unsigned short* cat     = (unsigned short*)p; p += (size_t)N * 256 * 2;
    unsigned short* hb      = (unsigned short*)p; p += (size_t)N * 64 * 2;
    unsigned short* wht     = (unsigned short*)p; p += (size_t)128 * 256 * 2;
    ull*            packed  = (ull*)p;            p += (size_t)N * 8;
    float*          dinv    = (float*)p;          p += (size_t)N * 4;
    int*            row_ptr = (int*)p;            p += (size_t)(N + 4) * 4;
    int*            bsum    = (int*)p;            p += (size_t)64 * 4;
    int*            rank    = (int*)p;            p += (size_t)E * 4;
    int2*           e_sw    = (int2*)p;           p += (size_t)E * 8;
    int2*           e_swn   = (int2*)p;           p += (size_t)E * 8;
    float* out = (float*)d_out;

    int eb   = (E + 255) / 256;
    int nb   = (N + 255) / 256;
    int nb64 = (N * 64 + 255) / 256;     // wave per node
    int gb   = (N + 127) / 128;
    int gb64 = (N + 63) / 64;
    int sb   = (N + 1023) / 1024;        // <= 64
    int s3b  = ((N + 3) / 4 + 256) / 256;

    // ---- CSR build + WhT conversion ----
    hipMemsetAsync(packed, 0, (size_t)N * 8, stream);
    wht_kernel<<<128, 256, 0, stream>>>(Wh, wht);
    histo_kernel<<<eb, 256, 0, stream>>>(dst, ew, packed, rank, E);
    dinv_kernel<<<nb, 256, 0, stream>>>(packed, dinv, N);
    scan1_kernel<<<sb, 256, 0, stream>>>(packed, row_ptr, bsum, N);
    scan2_kernel<<<1, 64, 0, stream>>>(bsum, sb);
    scan3_kernel<<<s3b, 256, 0, stream>>>(row_ptr, bsum, N, E);
    fill_kernel<<<eb, 256, 0, stream>>>(src, dst, ew, rank, row_ptr, dinv, e_sw, e_swn, E);

    // ---- layer 1 (no norm) ----
    gemm_hid_f32<<<gb, 256, 0, stream>>>(x, 128, 128, W1, hb, N);
    gather_plain<<<nb64, 256, 0, stream>>>(row_ptr, e_sw, hb, b1, cat, N);

    // ---- layers 2-4 (normalized) ----
    const float* Wl[3] = {W2, W3, W4};
    const float* bl[3] = {b2, b3, b4};
    for (int l = 1; l < 4; ++l) {
        gemm_hid_b<<<gb, 256, 0, stream>>>(cat + (size_t)(l - 1) * 64, 256, Wl[l - 1], hb, N);
        gather_norm<<<nb64, 256, 0, stream>>>(row_ptr, e_swn, hb, dinv,
                                              bl[l - 1], cat, l * 64, N);
    }

    // ---- final projection (MFMA) ----
    gemm_out_mfma<<<gb64, 256, 0, stream>>>(cat, wht, bh, out, N);
}

// Round 7
// 257.545 us; speedup vs baseline: 11.6332x; 1.1432x over previous
//
#include <hip/hip_runtime.h>
#include <hip/hip_bf16.h>

#define NEG_SLOP 0.2f
typedef unsigned long long ull;
typedef __attribute__((ext_vector_type(8))) short bf16x8;
typedef __attribute__((ext_vector_type(4))) float f32x4;

__device__ __forceinline__ float lrelu(float v) { return v > 0.0f ? v : NEG_SLOP * v; }

__device__ __forceinline__ float bf2f(unsigned short u) {
    union { unsigned int i; float f; } c; c.i = ((unsigned int)u) << 16; return c.f;
}
__device__ __forceinline__ unsigned short f2bf(float f) {
    union { float f; unsigned int i; } c; c.f = f;
    unsigned int r = c.i + 0x7FFF + ((c.i >> 16) & 1);  // round-nearest-even
    return (unsigned short)(r >> 16);
}

// ---------------- histogram: packed (cnt<<40 | fixed-point weight sum), emits rank ----------------
__global__ void histo_kernel(const int* __restrict__ dst, const float* __restrict__ ew,
                             ull* __restrict__ packed, int* __restrict__ rank, int n_edges) {
    int e = blockIdx.x * 256 + threadIdx.x;
    if (e >= n_edges) return;
    int d = dst[e];
    ull delta = (1ULL << 40) | (ull)(ew[e] * 4294967296.0f);
    ull old = atomicAdd(&packed[d], delta);
    rank[e] = (int)(old >> 40);
}

__global__ void dinv_kernel(const ull* __restrict__ packed, float* __restrict__ dinv, int n) {
    int i = blockIdx.x * 256 + threadIdx.x;
    if (i >= n) return;
    float deg = (float)(packed[i] & ((1ULL << 40) - 1)) * (1.0f / 4294967296.0f);
    dinv[i] = rsqrtf(deg + 1.0f);  // +1 self loop
}

// ---- 3-phase device-wide exclusive scan of counts ----
__global__ void scan1_kernel(const ull* __restrict__ packed, int* __restrict__ pre,
                             int* __restrict__ bsum, int n) {
    __shared__ int s[256];
    int t = threadIdx.x;
    int base = blockIdx.x * 1024 + t * 4;
    int c[4];
#pragma unroll
    for (int j = 0; j < 4; ++j) c[j] = (base + j < n) ? (int)(packed[base + j] >> 40) : 0;
    int tsum = c[0] + c[1] + c[2] + c[3];
    s[t] = tsum;
    __syncthreads();
    for (int off = 1; off < 256; off <<= 1) {
        int v = (t >= off) ? s[t - off] : 0;
        __syncthreads();
        s[t] += v;
        __syncthreads();
    }
    int ex = s[t] - tsum;
    if (t == 255) bsum[blockIdx.x] = s[255];
    int o[4];
    o[0] = ex; o[1] = ex + c[0]; o[2] = o[1] + c[1]; o[3] = o[2] + c[2];
    if (base + 3 < n) *(int4*)&pre[base] = make_int4(o[0], o[1], o[2], o[3]);
    else {
        for (int j = 0; j < 4; ++j) if (base + j < n) pre[base + j] = o[j];
    }
}

__global__ void scan2_kernel(int* __restrict__ bsum, int nb) {
    __shared__ int s[64];
    int t = threadIdx.x;
    int v = (t < nb) ? bsum[t] : 0;
    s[t] = v;
    __syncthreads();
    for (int off = 1; off < 64; off <<= 1) {
        int u = (t >= off) ? s[t - off] : 0;
        __syncthreads();
        s[t] += u;
        __syncthreads();
    }
    if (t < nb) bsum[t] = s[t] - v;
}

__global__ void scan3_kernel(int* __restrict__ rp, const int* __restrict__ bsum,
                             int n, int n_edges) {
    int t = blockIdx.x * 256 + threadIdx.x;
    int base = t * 4;
    if (base >= n) {
        if (base == ((n + 3) & ~3)) rp[n] = n_edges;
        return;
    }
    int boff = bsum[base >> 10];
    if (base + 3 < n) {
        int4 v = *(const int4*)&rp[base];
        v.x += boff; v.y += boff; v.z += boff; v.w += boff;
        *(int4*)&rp[base] = v;
    } else {
        for (int j = 0; j < 4 && base + j < n; ++j) rp[base + j] += boff;
        rp[n] = n_edges;
    }
}

// ---------------- CSR fill: atomic-free, single (src, w) record ----------------
__global__ void fill_kernel(const int* __restrict__ src, const int* __restrict__ dst,
                            const float* __restrict__ ew, const int* __restrict__ rank,
                            const int* __restrict__ rp, int2* __restrict__ e_sw, int n_edges) {
    int e = blockIdx.x * 256 + threadIdx.x;
    if (e >= n_edges) return;
    int pos = rp[dst[e]] + rank[e];
    e_sw[pos] = make_int2(src[e], __float_as_int(ew[e]));
}

// ---------------- gathers: wave/node, 4 edge-groups x 16 feature-lanes, unroll-4 ----------------
__global__ void gather_plain(const int* __restrict__ rp, const int2* __restrict__ e_sw,
                             const unsigned short* __restrict__ hb,
                             const float* __restrict__ b, unsigned short* __restrict__ cat, int n) {
    int node = (blockIdx.x * 256 + threadIdx.x) >> 6;
    if (node >= n) return;
    int lane = threadIdx.x & 63;
    int eg = lane >> 4;
    int f0 = (lane & 15) * 4;
    int lo = rp[node], hi = rp[node + 1];
    float a0 = 0.f, a1 = 0.f, a2 = 0.f, a3 = 0.f;
    for (int k = lo + eg; k < hi; k += 16) {
        int k1 = k + 4, k2 = k + 8, k3 = k + 12;
        int2 p0 = e_sw[k];
        int2 p1 = e_sw[k1 < hi ? k1 : k];
        int2 p2 = e_sw[k2 < hi ? k2 : k];
        int2 p3 = e_sw[k3 < hi ? k3 : k];
        float w0 = __int_as_float(p0.y);
        float w1 = k1 < hi ? __int_as_float(p1.y) : 0.f;
        float w2 = k2 < hi ? __int_as_float(p2.y) : 0.f;
        float w3 = k3 < hi ? __int_as_float(p3.y) : 0.f;
        ushort4 u0 = *(const ushort4*)&hb[(size_t)p0.x * 64 + f0];
        ushort4 u1 = *(const ushort4*)&hb[(size_t)p1.x * 64 + f0];
        ushort4 u2 = *(const ushort4*)&hb[(size_t)p2.x * 64 + f0];
        ushort4 u3 = *(const ushort4*)&hb[(size_t)p3.x * 64 + f0];
        a0 += w0 * bf2f(u0.x) + w1 * bf2f(u1.x) + w2 * bf2f(u2.x) + w3 * bf2f(u3.x);
        a1 += w0 * bf2f(u0.y) + w1 * bf2f(u1.y) + w2 * bf2f(u2.y) + w3 * bf2f(u3.y);
        a2 += w0 * bf2f(u0.z) + w1 * bf2f(u1.z) + w2 * bf2f(u2.z) + w3 * bf2f(u3.z);
        a3 += w0 * bf2f(u0.w) + w1 * bf2f(u1.w) + w2 * bf2f(u2.w) + w3 * bf2f(u3.w);
    }
    a0 += __shfl_xor(a0, 16, 64); a0 += __shfl_xor(a0, 32, 64);
    a1 += __shfl_xor(a1, 16, 64); a1 += __shfl_xor(a1, 32, 64);
    a2 += __shfl_xor(a2, 16, 64); a2 += __shfl_xor(a2, 32, 64);
    a3 += __shfl_xor(a3, 16, 64); a3 += __shfl_xor(a3, 32, 64);
    if (eg == 0) {
        ushort4 o;
        o.x = f2bf(lrelu(a0 + b[f0 + 0])); o.y = f2bf(lrelu(a1 + b[f0 + 1]));
        o.z = f2bf(lrelu(a2 + b[f0 + 2])); o.w = f2bf(lrelu(a3 + b[f0 + 3]));
        *(ushort4*)&cat[(size_t)node * 256 + f0] = o;
    }
}

// hb here holds hb2 = dinv[row] * (h @ W); result = lrelu(dinv[d]*(sum + hb2[d]) + b)
__global__ void gather_norm(const int* __restrict__ rp, const int2* __restrict__ e_sw,
                            const unsigned short* __restrict__ hb,
                            const float* __restrict__ dinv, const float* __restrict__ b,
                            unsigned short* __restrict__ cat, int col_off, int n) {
    int node = (blockIdx.x * 256 + threadIdx.x) >> 6;
    if (node >= n) return;
    int lane = threadIdx.x & 63;
    int eg = lane >> 4;
    int f0 = (lane & 15) * 4;
    int lo = rp[node], hi = rp[node + 1];
    float a0 = 0.f, a1 = 0.f, a2 = 0.f, a3 = 0.f;
    for (int k = lo + eg; k < hi; k += 16) {
        int k1 = k + 4, k2 = k + 8, k3 = k + 12;
        int2 p0 = e_sw[k];
        int2 p1 = e_sw[k1 < hi ? k1 : k];
        int2 p2 = e_sw[k2 < hi ? k2 : k];
        int2 p3 = e_sw[k3 < hi ? k3 : k];
        float w0 = __int_as_float(p0.y);
        float w1 = k1 < hi ? __int_as_float(p1.y) : 0.f;
        float w2 = k2 < hi ? __int_as_float(p2.y) : 0.f;
        float w3 = k3 < hi ? __int_as_float(p3.y) : 0.f;
        ushort4 u0 = *(const ushort4*)&hb[(size_t)p0.x * 64 + f0];
        ushort4 u1 = *(const ushort4*)&hb[(size_t)p1.x * 64 + f0];
        ushort4 u2 = *(const ushort4*)&hb[(size_t)p2.x * 64 + f0];
        ushort4 u3 = *(const ushort4*)&hb[(size_t)p3.x * 64 + f0];
        a0 += w0 * bf2f(u0.x) + w1 * bf2f(u1.x) + w2 * bf2f(u2.x) + w3 * bf2f(u3.x);
        a1 += w0 * bf2f(u0.y) + w1 * bf2f(u1.y) + w2 * bf2f(u2.y) + w3 * bf2f(u3.y);
        a2 += w0 * bf2f(u0.z) + w1 * bf2f(u1.z) + w2 * bf2f(u2.z) + w3 * bf2f(u3.z);
        a3 += w0 * bf2f(u0.w) + w1 * bf2f(u1.w) + w2 * bf2f(u2.w) + w3 * bf2f(u3.w);
    }
    a0 += __shfl_xor(a0, 16, 64); a0 += __shfl_xor(a0, 32, 64);
    a1 += __shfl_xor(a1, 16, 64); a1 += __shfl_xor(a1, 32, 64);
    a2 += __shfl_xor(a2, 16, 64); a2 += __shfl_xor(a2, 32, 64);
    a3 += __shfl_xor(a3, 16, 64); a3 += __shfl_xor(a3, 32, 64);
    if (eg == 0) {
        float di = dinv[node];
        ushort4 h = *(const ushort4*)&hb[(size_t)node * 64 + f0];
        ushort4 o;
        o.x = f2bf(lrelu(di * (a0 + bf2f(h.x)) + b[f0 + 0]));
        o.y = f2bf(lrelu(di * (a1 + bf2f(h.y)) + b[f0 + 1]));
        o.z = f2bf(lrelu(di * (a2 + bf2f(h.z)) + b[f0 + 2]));
        o.w = f2bf(lrelu(di * (a3 + bf2f(h.w)) + b[f0 + 3]));
        *(ushort4*)&cat[(size_t)node * 256 + col_off + f0] = o;
    }
}

// ---------------- skinny GEMM (fp32 in): [N x 128] @ [128 x 64] -> bf16 hW (layer 1) ----------------
__global__ __launch_bounds__(256) void gemm_hid_f32(
    const float* __restrict__ in, int in_stride, int K,
    const float* __restrict__ W, unsigned short* __restrict__ outb, int n_rows) {
    __shared__ float Ws[64 * 64];
    __shared__ float XsT[64 * 132];
    const int tid = threadIdx.x;
    const int tc = tid & 15, tr = tid >> 4;
    const int row0 = blockIdx.x * 128;
    float acc[8][4] = {};
    for (int kc = 0; kc < K; kc += 64) {
        __syncthreads();
        for (int i = tid; i < 64 * 64; i += 256) Ws[i] = W[kc * 64 + i];
        {
            int k = tid & 63, rq = tid >> 6;
            for (int i = 0; i < 32; ++i) {
                int r = rq * 32 + i;
                int rr = row0 + r; if (rr >= n_rows) rr = n_rows - 1;
                XsT[k * 132 + r] = in[(size_t)rr * in_stride + kc + k];
            }
        }
        __syncthreads();
        for (int kk = 0; kk < 64; ++kk) {
            float4 w4 = *(const float4*)&Ws[kk * 64 + tc * 4];
            float4 aA = *(const float4*)&XsT[kk * 132 + tr * 8];
            float4 aB = *(const float4*)&XsT[kk * 132 + tr * 8 + 4];
            float a[8] = {aA.x, aA.y, aA.z, aA.w, aB.x, aB.y, aB.z, aB.w};
#pragma unroll
            for (int i = 0; i < 8; ++i) {
                acc[i][0] += a[i] * w4.x; acc[i][1] += a[i] * w4.y;
                acc[i][2] += a[i] * w4.z; acc[i][3] += a[i] * w4.w;
            }
        }
    }
#pragma unroll
    for (int i = 0; i < 8; ++i) {
        int r = row0 + tr * 8 + i;
        if (r >= n_rows) break;
        ushort4 o;
        o.x = f2bf(acc[i][0]); o.y = f2bf(acc[i][1]);
        o.z = f2bf(acc[i][2]); o.w = f2bf(acc[i][3]);
        *(ushort4*)&outb[(size_t)r * 64 + tc * 4] = o;
    }
}

// ---------------- skinny GEMM (bf16 in): [N x 64] @ [64 x 64] -> bf16 hb2 = dinv*out (layers 2-4) ----------------
__global__ __launch_bounds__(256) void gemm_hid_b(
    const unsigned short* __restrict__ in, int in_stride,
    const float* __restrict__ W, const float* __restrict__ dinv,
    unsigned short* __restrict__ outb, int n_rows) {
    __shared__ float Ws[64 * 64];
    __shared__ float XsT[64 * 132];
    const int tid = threadIdx.x;
    const int tc = tid & 15, tr = tid >> 4;
    const int row0 = blockIdx.x * 128;
    float acc[8][4] = {};
    for (int i = tid; i < 64 * 64; i += 256) Ws[i] = W[i];
    {   // stage bf16 rows as ushort2 (vectorized)
        int k2 = tid & 31, rq = tid >> 5;
        for (int i = 0; i < 16; ++i) {
            int r = rq * 16 + i;
            int rr = row0 + r; if (rr >= n_rows) rr = n_rows - 1;
            ushort2 u = *(const ushort2*)&in[(size_t)rr * in_stride + 2 * k2];
            XsT[(2 * k2) * 132 + r] = bf2f(u.x);
            XsT[(2 * k2 + 1) * 132 + r] = bf2f(u.y);
        }
    }
    __syncthreads();
    for (int kk = 0; kk < 64; ++kk) {
        float4 w4 = *(const float4*)&Ws[kk * 64 + tc * 4];
        float4 aA = *(const float4*)&XsT[kk * 132 + tr * 8];
        float4 aB = *(const float4*)&XsT[kk * 132 + tr * 8 + 4];
        float a[8] = {aA.x, aA.y, aA.z, aA.w, aB.x, aB.y, aB.z, aB.w};
#pragma unroll
        for (int i = 0; i < 8; ++i) {
            acc[i][0] += a[i] * w4.x; acc[i][1] += a[i] * w4.y;
            acc[i][2] += a[i] * w4.z; acc[i][3] += a[i] * w4.w;
        }
    }
#pragma unroll
    for (int i = 0; i < 8; ++i) {
        int r = row0 + tr * 8 + i;
        if (r >= n_rows) break;
        float di = dinv[r];
        ushort4 o;
        o.x = f2bf(acc[i][0] * di); o.y = f2bf(acc[i][1] * di);
        o.z = f2bf(acc[i][2] * di); o.w = f2bf(acc[i][3] * di);
        *(ushort4*)&outb[(size_t)r * 64 + tc * 4] = o;
    }
}

// ---------------- Wh fp32 [256][128] -> WhT bf16 [128][256] ----------------
__global__ void wht_kernel(const float* __restrict__ Wh, unsigned short* __restrict__ wht) {
    int idx = blockIdx.x * 256 + threadIdx.x;
    if (idx >= 256 * 128) return;
    int k = idx >> 7, c = idx & 127;
    wht[(size_t)c * 256 + k] = f2bf(Wh[idx]);
}

// ---------------- final GEMM via MFMA: cat(bf16)[N x 256] @ Wh[256 x 128] + bh ----------------
__global__ __launch_bounds__(256) void gemm_out_mfma(
    const unsigned short* __restrict__ cat, const unsigned short* __restrict__ whT,
    const float* __restrict__ bh, float* __restrict__ out, int n_rows) {
    __shared__ __align__(16) char As[64 * 128];    // [row][k] bf16, swizzled
    __shared__ __align__(16) char Bs[128 * 128];   // [col][k] bf16, swizzled
    const int tid = threadIdx.x;
    const int wid = tid >> 6, lane = tid & 63;
    const int row0 = blockIdx.x * 64;
    const int lrow = lane & 15, kg = lane >> 4;
    f32x4 acc[8] = {};
    for (int kc = 0; kc < 4; ++kc) {
        __syncthreads();
        {   // stage A: 64 rows x 64 k bf16
            int row = tid >> 2, seg = tid & 3;
            int rr = row0 + row; if (rr >= n_rows) rr = n_rows - 1;
            const int4* g = (const int4*)&cat[(size_t)rr * 256 + kc * 64 + seg * 16];
            int4 u0 = g[0], u1 = g[1];
            int sw = (row & 7) << 4;
            int base = row * 128 + seg * 32;
            *(int4*)(As + (base ^ sw)) = u0;
            *(int4*)(As + ((base + 16) ^ sw)) = u1;
        }
        {   // stage B: 128 cols x 64 k bf16
            int c = tid >> 1, seg = tid & 1;
            const int4* g = (const int4*)&whT[(size_t)c * 256 + kc * 64 + seg * 32];
            int sw = (c & 7) << 4;
            int base = c * 128 + seg * 64;
#pragma unroll
            for (int i = 0; i < 4; ++i)
                *(int4*)(Bs + ((base + i * 16) ^ sw)) = g[i];
        }
        __syncthreads();
        int arow = wid * 16 + lrow;
        int asw = (arow & 7) << 4;
#pragma unroll
        for (int ks = 0; ks < 2; ++ks) {
            bf16x8 af = *(bf16x8*)(As + ((arow * 128 + ks * 64 + kg * 16) ^ asw));
#pragma unroll
            for (int cf = 0; cf < 8; ++cf) {
                int c = cf * 16 + lrow;
                bf16x8 bf = *(bf16x8*)(Bs + ((c * 128 + ks * 64 + kg * 16) ^ ((c & 7) << 4)));
                acc[cf] = __builtin_amdgcn_mfma_f32_16x16x32_bf16(af, bf, acc[cf], 0, 0, 0);
            }
        }
    }
    int lrow4 = (lane >> 4) * 4;
#pragma unroll
    for (int cf = 0; cf < 8; ++cf) {
        int col = cf * 16 + lrow;
        float bias = bh[col];
#pragma unroll
        for (int reg = 0; reg < 4; ++reg) {
            int r = row0 + wid * 16 + lrow4 + reg;
            if (r < n_rows) out[(size_t)r * 128 + col] = acc[cf][reg] + bias;
        }
    }
}

extern "C" void kernel_launch(void* const* d_in, const int* in_sizes, int n_in,
                              void* d_out, int out_size, void* d_ws, size_t ws_size,
                              hipStream_t stream) {
    const float* x  = (const float*)d_in[0];
    const int*   ei = (const int*)d_in[1];
    const float* ew = (const float*)d_in[2];
    const float* W1 = (const float*)d_in[3];
    const float* b1 = (const float*)d_in[4];
    const float* W2 = (const float*)d_in[5];
    const float* b2 = (const float*)d_in[6];
    const float* W3 = (const float*)d_in[7];
    const float* b3 = (const float*)d_in[8];
    const float* W4 = (const float*)d_in[9];
    const float* b4 = (const float*)d_in[10];
    const float* Wh = (const float*)d_in[11];
    const float* bh = (const float*)d_in[12];

    const int E = in_sizes[2];          // 800000
    const int N = in_sizes[0] / 128;    // 50000
    const int* src = ei;
    const int* dst = ei + E;

    char* p = (char*)d_ws;
    unsigned short* cat     = (unsigned short*)p; p += (size_t)N * 256 * 2;
    unsigned short* hb      = (unsigned short*)p; p += (size_t)N * 64 * 2;
    unsigned short* wht     = (unsigned short*)p; p += (size_t)128 * 256 * 2;
    ull*            packed  = (ull*)p;            p += (size_t)N * 8;
    float*          dinv    = (float*)p;          p += (size_t)N * 4;
    int*            row_ptr = (int*)p;            p += (size_t)(N + 4) * 4;
    int*            bsum    = (int*)p;            p += (size_t)64 * 4;
    int*            rank    = (int*)p;            p += (size_t)E * 4;
    int2*           e_sw    = (int2*)p;           p += (size_t)E * 8;
    float* out = (float*)d_out;

    int eb   = (E + 255) / 256;
    int nb   = (N + 255) / 256;
    int nb64 = (N * 64 + 255) / 256;     // wave per node
    int gb   = (N + 127) / 128;
    int gb64 = (N + 63) / 64;
    int sb   = (N + 1023) / 1024;        // <= 64
    int s3b  = ((N + 3) / 4 + 256) / 256;

    // ---- CSR build + WhT conversion ----
    hipMemsetAsync(packed, 0, (size_t)N * 8, stream);
    wht_kernel<<<128, 256, 0, stream>>>(Wh, wht);
    histo_kernel<<<eb, 256, 0, stream>>>(dst, ew, packed, rank, E);
    dinv_kernel<<<nb, 256, 0, stream>>>(packed, dinv, N);
    scan1_kernel<<<sb, 256, 0, stream>>>(packed, row_ptr, bsum, N);
    scan2_kernel<<<1, 64, 0, stream>>>(bsum, sb);
    scan3_kernel<<<s3b, 256, 0, stream>>>(row_ptr, bsum, N, E);
    fill_kernel<<<eb, 256, 0, stream>>>(src, dst, ew, rank, row_ptr, e_sw, E);

    // ---- layer 1 (no norm) ----
    gemm_hid_f32<<<gb, 256, 0, stream>>>(x, 128, 128, W1, hb, N);
    gather_plain<<<nb64, 256, 0, stream>>>(row_ptr, e_sw, hb, b1, cat, N);

    // ---- layers 2-4 (normalized; hb holds dinv-scaled hidden) ----
    const float* Wl[3] = {W2, W3, W4};
    const float* bl[3] = {b2, b3, b4};
    for (int l = 1; l < 4; ++l) {
        gemm_hid_b<<<gb, 256, 0, stream>>>(cat + (size_t)(l - 1) * 64, 256, Wl[l - 1],
                                           dinv, hb, N);
        gather_norm<<<nb64, 256, 0, stream>>>(row_ptr, e_sw, hb, dinv,
                                              bl[l - 1], cat, l * 64, N);
    }

    // ---- final projection (MFMA) ----
    gemm_out_mfma<<<gb64, 256, 0, stream>>>(cat, wht, bh, out, N);
}